// Round 9
// baseline (4344.989 us; speedup 1.0000x reference)
//
#include <hip/hip_runtime.h>
#include <hip/hip_bf16.h>

// Problem constants: B=32, S=128, T=20 (19 dec steps), H=1024, D=512, K_attn=100, V=32000
// Inputs float32; output d_out float32 (B,19,V).
// Encoder: round-8 kernel with ONE change (single-variable experiment):
// signal = release fetch_add on PER-BLOCK flag slot + parallel 64-lane poll,
// replacing the shared counter whose 64 same-address RMWs serialize (~16us/step).
// Staging loop byte-identical to the passing round-4/8 version (rounds 5-7
// proved batched pure-load staging deterministically corrupts — do not touch).

using bf16 = __hip_bfloat16;
typedef __attribute__((ext_vector_type(8))) __bf16 bf16x8;
typedef __attribute__((ext_vector_type(4))) float f32x4;

__device__ __forceinline__ bf16x8 ld8(const bf16* p) {
    return *reinterpret_cast<const bf16x8*>(p);
}
__device__ __forceinline__ float b2f(bf16 v) { return __bfloat162float(v); }
__device__ __forceinline__ bf16 f2b(float v) { return __float2bfloat16(v); }
__device__ __forceinline__ unsigned short b2u(bf16 v) {
    unsigned short u; __builtin_memcpy(&u, &v, 2); return u;
}
__device__ __forceinline__ float sigf(float x) { return 1.0f / (1.0f + expf(-x)); }

#define MFMA(a, b, c) __builtin_amdgcn_mfma_f32_16x16x32_bf16((a), (b), (c), 0, 0, 0)

// ---------------------------------------------------------------------------
// f32 -> bf16 conversion for weight tensors. blockIdx.y selects tensor.
struct ConvDesc { const float* src; bf16* dst; int n; };
struct ConvTable { ConvDesc d[13]; };

__global__ __launch_bounds__(256) void k_conv(ConvTable tab) {
    ConvDesc cd = tab.d[blockIdx.y];
    int stride = gridDim.x * blockDim.x * 4;
    for (int i = (blockIdx.x * blockDim.x + threadIdx.x) * 4; i < cd.n; i += stride) {
        float4 v = *reinterpret_cast<const float4*>(cd.src + i);
        bf16 tmp[4] = {f2b(v.x), f2b(v.y), f2b(v.z), f2b(v.w)};
        *reinterpret_cast<ushort4*>(cd.dst + i) = *reinterpret_cast<const ushort4*>(tmp);
    }
}

// ---------------------------------------------------------------------------
// Gather bf16 embedding rows (512 bf16 = 256 u32 per row), one block per row.
__global__ __launch_bounds__(256) void k_gather(const unsigned int* __restrict__ table,
                                                const int* __restrict__ idx,
                                                unsigned int* __restrict__ out) {
    int r = blockIdx.x;
    out[(size_t)r * 256 + threadIdx.x] = table[(size_t)idx[r] * 256 + threadIdx.x];
}

// ---------------------------------------------------------------------------
// Generic big tiled GEMM: C = A(MxK) @ Bw(NxK)^T  (both row-major, bf16)
// mode 0: outF fp32 = C + bias ; mode 1: tanh ; mode 2: logits remap ; mode 3: bf16+bias
// xcdmap=1: group M-tiles of one N-strip consecutively on one XCD (L2 reuse).
__global__ __launch_bounds__(256) void k_gemm_bt(const bf16* __restrict__ A,
                                                 const bf16* __restrict__ Bw,
                                                 const float* __restrict__ bias,
                                                 float* __restrict__ outF,
                                                 bf16* __restrict__ outB,
                                                 int M, int N, int K, int ldo,
                                                 int ntN, int mode, int xcdmap) {
    int bx = blockIdx.x;
    int mt, nt;
    if (xcdmap) {
        int ntM = (M + 127) >> 7;
        int x = bx & 7, w = bx >> 3;
        mt = w % ntM;
        nt = (w / ntM) * 8 + x;
        if (nt >= ntN) return;
    } else {
        mt = bx / ntN;
        nt = bx % ntN;
    }
    int tid = threadIdx.x, wv = tid >> 6, l = tid & 63;
    int m0 = mt * 128 + (wv >> 1) * 64;
    int n0 = nt * 128 + (wv & 1) * 64;
    int r = l & 15, ko = (l >> 4) * 8;

    const bf16* ap[4];
    const bf16* bp[4];
#pragma unroll
    for (int i = 0; i < 4; ++i) {
        int row = m0 + i * 16 + r;
        if (row > M - 1) row = M - 1;
        ap[i] = A + (size_t)row * K + ko;
    }
#pragma unroll
    for (int j = 0; j < 4; ++j) {
        int n = n0 + j * 16 + r;
        if (n > N - 1) n = N - 1;
        bp[j] = Bw + (size_t)n * K + ko;
    }

    f32x4 zv = {0.f, 0.f, 0.f, 0.f};
    f32x4 acc[4][4];
#pragma unroll
    for (int i = 0; i < 4; ++i)
#pragma unroll
        for (int j = 0; j < 4; ++j) acc[i][j] = zv;

    int nk = K >> 5;
    for (int kk = 0; kk < nk; ++kk) {
        bf16x8 af[4], bfv[4];
#pragma unroll
        for (int i = 0; i < 4; ++i) af[i] = ld8(ap[i] + kk * 32);
#pragma unroll
        for (int j = 0; j < 4; ++j) bfv[j] = ld8(bp[j] + kk * 32);
#pragma unroll
        for (int i = 0; i < 4; ++i)
#pragma unroll
            for (int j = 0; j < 4; ++j) acc[i][j] = MFMA(af[i], bfv[j], acc[i][j]);
    }

    int ccol = l & 15, cr = (l >> 4) * 4;
#pragma unroll
    for (int i = 0; i < 4; ++i) {
#pragma unroll
        for (int j = 0; j < 4; ++j) {
            int n = n0 + j * 16 + ccol;
            if (n >= N) continue;
            float bv = bias ? bias[n] : 0.f;
#pragma unroll
            for (int q = 0; q < 4; ++q) {
                int row = m0 + i * 16 + cr + q;
                if (row >= M) continue;
                float v = acc[i][j][q] + bv;
                if (mode == 1) v = tanhf(v);
                if (mode == 2) {
                    outF[((size_t)(row & 31) * 19 + (size_t)(row >> 5)) * 32000 + n] = v;
                } else if (mode == 3) {
                    outB[(size_t)row * ldo + n] = f2b(v);
                } else {
                    outF[(size_t)row * ldo + n] = v;
                }
            }
        }
    }
}

// ---------------------------------------------------------------------------
// Small-M GEMM: one 16x16 tile per block (64 threads = 1 wave).
// act: 0 none, 1 relu, 2 tanh.
__global__ __launch_bounds__(64) void k_gemm_sm(const bf16* __restrict__ A,
                                                const bf16* __restrict__ W,
                                                const float* __restrict__ bias,
                                                float* __restrict__ outF, int ldof,
                                                bf16* __restrict__ outB, int ldob,
                                                int K, int ntN, int act) {
    int bx = blockIdx.x;
    int mt = bx / ntN, nt = bx % ntN;
    int l = threadIdx.x;
    int r = l & 15, ko = (l >> 4) * 8;
    const bf16* ap = A + (size_t)(mt * 16 + r) * K + ko;
    const bf16* bp = W + (size_t)(nt * 16 + r) * K + ko;
    f32x4 acc = {0.f, 0.f, 0.f, 0.f};
    int nk = K >> 5;
#pragma unroll 4
    for (int kk = 0; kk < nk; ++kk) acc = MFMA(ld8(ap + kk * 32), ld8(bp + kk * 32), acc);
    int n = nt * 16 + (l & 15);
    int cr = (l >> 4) * 4;
    float bv = bias ? bias[n] : 0.f;
#pragma unroll
    for (int q = 0; q < 4; ++q) {
        int row = mt * 16 + cr + q;
        float v = acc[q] + bv;
        if (act == 1) v = fmaxf(v, 0.f);
        if (act == 2) v = tanhf(v);
        if (outF) outF[(size_t)row * ldof + n] = v;
        if (outB) outB[(size_t)row * ldob + n] = f2b(v);
    }
}

// ---------------------------------------------------------------------------
// Persistent encoder, 128 LSTM steps. Round-8 kernel; ONLY the signal path
// changed: per-block flag slot (release fetch_add, no same-address contention)
// + parallel 64-lane poll. Staging loop byte-identical to round 4/8.
__global__ __launch_bounds__(256, 1) void k_enc_all(const bf16* __restrict__ Zx,
                                                    const bf16* __restrict__ Whh,
                                                    const float* __restrict__ bih,
                                                    const float* __restrict__ bhh,
                                                    const int* __restrict__ lens,
                                                    unsigned int* __restrict__ hbw0,
                                                    unsigned int* __restrict__ hbw1,
                                                    bf16* __restrict__ cbT,
                                                    bf16* __restrict__ SH,
                                                    int* __restrict__ flags) {
    __shared__ bf16 hlds[32][1024];          // 64KB staged h, XOR-swizzled 16B units
    __shared__ float zl[4][32][16];          // 8KB gate outputs
    __shared__ unsigned short hpub[32][16];  // 1KB publish staging
    unsigned int* hldsw = (unsigned int*)hlds;
    const bf16x8* hldsv = (const bf16x8*)hlds;

    int j0 = blockIdx.x * 16;
    int tid = threadIdx.x;
    int g = tid >> 6, l = tid & 63;
    int r = l & 15, ko = (l >> 4) * 8;

    // Whh slice -> registers (16 rows x 1024 K per wave), loaded once.
    bf16x8 wreg[32];
    {
        const bf16* wp = Whh + (size_t)(g * 1024 + j0 + r) * 1024 + ko;
#pragma unroll
        for (int kk = 0; kk < 32; ++kk) wreg[kk] = ld8(wp + kk * 32);
    }

    int b0 = tid >> 4, ji = tid & 15;
    int b1 = b0 + 16;
    int j = j0 + ji;
    float bs[4];
#pragma unroll
    for (int gg = 0; gg < 4; ++gg) bs[gg] = bih[gg * 1024 + j] + bhh[gg * 1024 + j];
    int len0 = lens[b0], len1 = lens[b1];
    float h0 = 0.f, c0 = 0.f, h1 = 0.f, c1 = 0.f;
    const bf16* zx0 = Zx + (size_t)(b0 * 128) * 4096 + j;
    const bf16* zx1 = Zx + (size_t)(b1 * 128) * 4096 + j;
    int ccol = l & 15, cr = (l >> 4) * 4;
    int rk = r & 7;  // XOR swizzle key (same for rows r and r+16)

    for (int t = 0; t < 128; ++t) {
        // Prefetch Zx[t] (independent of barrier) — hides LLC latency under spin.
        float za0[4], za1[4];
#pragma unroll
        for (int gg = 0; gg < 4; ++gg) {
            za0[gg] = b2f(zx0[(size_t)t * 4096 + gg * 1024]);
            za1[gg] = b2f(zx1[(size_t)t * 4096 + gg * 1024]);
        }

        // Wait for all 64 producers of h_t (t=0: initial zeros from memset).
        // SINGLE CHANGE vs round 8: parallel per-lane poll of per-block slots.
        if (t > 0) {
            if (tid < 64) {
                const int* fp = flags + (t - 1) * 64;
                while (true) {
                    int v = __hip_atomic_load(fp + l, __ATOMIC_RELAXED,
                                              __HIP_MEMORY_SCOPE_AGENT);
                    if (__all(v != 0)) break;
                    __builtin_amdgcn_s_sleep(1);
                }
                (void)__hip_atomic_load(fp + l, __ATOMIC_ACQUIRE,
                                        __HIP_MEMORY_SCOPE_AGENT);
            }
            __syncthreads();
        }

        // Stage h_t (64KB) LLC -> LDS, swizzled: unit u -> u ^ (row & 7).
        // Byte-identical to round 4/8 — DO NOT reschedule (rounds 5-7).
        const unsigned int* hw = (t & 1) ? hbw1 : hbw0;
#pragma unroll 4
        for (int i = 0; i < 64; ++i) {
            int d = i * 256 + tid;
            int b = d >> 9, w = d & 511;
            unsigned int v = __hip_atomic_load(hw + d, __ATOMIC_RELAXED,
                                               __HIP_MEMORY_SCOPE_AGENT);
            hldsw[b * 512 + ((((w >> 2) ^ (b & 7)) << 2) | (w & 3))] = v;
        }
        __syncthreads();

        // z[g] slice = h @ Whh[g-slice]^T from LDS.
        f32x4 acc0 = {0.f, 0.f, 0.f, 0.f}, acc1 = {0.f, 0.f, 0.f, 0.f};
#pragma unroll
        for (int kk = 0; kk < 32; ++kk) {
            int u = kk * 4 + (l >> 4);
            acc0 = MFMA(hldsv[r * 128 + (u ^ rk)], wreg[kk], acc0);
            acc1 = MFMA(hldsv[(16 + r) * 128 + (u ^ rk)], wreg[kk], acc1);
        }
#pragma unroll
        for (int q = 0; q < 4; ++q) {
            zl[g][cr + q][ccol] = acc0[q];
            zl[g][16 + cr + q][ccol] = acc1[q];
        }
        __syncthreads();

        // Fused pointwise: this thread owns (b0,j) and (b1,j).
        {
            float zi = zl[0][b0][ji] + za0[0] + bs[0];
            float zf = zl[1][b0][ji] + za0[1] + bs[1];
            float zg = zl[2][b0][ji] + za0[2] + bs[2];
            float zo = zl[3][b0][ji] + za0[3] + bs[3];
            float cn = sigf(zf) * c0 + sigf(zi) * tanhf(zg);
            float hn = sigf(zo) * tanhf(cn);
            bool msk = t < len0;
            if (msk) { h0 = hn; c0 = cn; }
            hpub[b0][ji] = b2u(f2b(h0));
            SH[((size_t)b0 * 128 + t) * 1024 + j] = msk ? f2b(hn) : f2b(0.f);
        }
        {
            float zi = zl[0][b1][ji] + za1[0] + bs[0];
            float zf = zl[1][b1][ji] + za1[1] + bs[1];
            float zg = zl[2][b1][ji] + za1[2] + bs[2];
            float zo = zl[3][b1][ji] + za1[3] + bs[3];
            float cn = sigf(zf) * c1 + sigf(zi) * tanhf(zg);
            float hn = sigf(zo) * tanhf(cn);
            bool msk = t < len1;
            if (msk) { h1 = hn; c1 = cn; }
            hpub[b1][ji] = b2u(f2b(h1));
            SH[((size_t)b1 * 128 + t) * 1024 + j] = msk ? f2b(hn) : f2b(0.f);
        }
        if (t == 127) {
            cbT[b0 * 1024 + j] = f2b(c0);
            cbT[b1 * 1024 + j] = f2b(c1);
        }
        __syncthreads();

        // Publish this block's h_{t+1} slice (32 b x 16 j = 256 u32) to LLC.
        unsigned int* hwn = (t & 1) ? hbw0 : hbw1;
        {
            int pb = tid >> 3, pw = tid & 7;
            unsigned int val = (unsigned int)hpub[pb][2 * pw] |
                               ((unsigned int)hpub[pb][2 * pw + 1] << 16);
            __hip_atomic_store(hwn + (size_t)pb * 512 + (j0 >> 1) + pw, val,
                               __ATOMIC_RELAXED, __HIP_MEMORY_SCOPE_AGENT);
        }
        __syncthreads();  // per-wave vmcnt(0) drained before barrier => stores acked
        if (tid == 0)
            __hip_atomic_fetch_add(flags + t * 64 + blockIdx.x, 1, __ATOMIC_RELEASE,
                                   __HIP_MEMORY_SCOPE_AGENT);
    }
}

// ---------------------------------------------------------------------------
// Decoder attention step. Grid 128 = 32 batches x 4 j-chunks (256 cols each).
// a_key precomputed (akey, 32x112 fp32, first 100 valid); qvB in bf16.
__global__ __launch_bounds__(256) void k_attn(const bf16* __restrict__ embedB,
                                              const int* __restrict__ trg,
                                              const float* __restrict__ akey,
                                              const float* __restrict__ qkB,
                                              const bf16* __restrict__ qvBb,
                                              const int* __restrict__ lens,
                                              bf16* __restrict__ xin,
                                              bf16* __restrict__ featA, int t) {
    int b = blockIdx.x >> 2, chunk = blockIdx.x & 3;
    int tid = threadIdx.x;
    if (chunk == 0) {
        const unsigned int* er = (const unsigned int*)(embedB + (size_t)trg[b * 20 + t] * 512);
        ((unsigned int*)(xin + (size_t)b * 1536))[tid] = er[tid];
    }

    __shared__ float ak[100];
    __shared__ float ew[128];
    __shared__ float mxs, inv_s;

    if (tid < 100) ak[tid] = akey[b * 112 + tid];
    __syncthreads();

    if (tid < 128) {
        const float* qr = qkB + ((size_t)b * 128 + tid) * 100;
        float e = 0.f;
#pragma unroll 4
        for (int k = 0; k < 100; ++k) e += qr[k] * ak[k];
        ew[tid] = (tid < lens[b]) ? e : -INFINITY;
    }
    __syncthreads();
    if (tid < 64) {
        float m = fmaxf(ew[tid], ew[tid + 64]);
#pragma unroll
        for (int off = 32; off; off >>= 1) m = fmaxf(m, __shfl_down(m, off));
        if (tid == 0) mxs = m;
    }
    __syncthreads();
    if (tid < 128) ew[tid] = expf(ew[tid] - mxs);  // masked -> 0
    __syncthreads();
    if (tid < 64) {
        float s = ew[tid] + ew[tid + 64];
#pragma unroll
        for (int off = 32; off; off >>= 1) s += __shfl_down(s, off);
        if (tid == 0) inv_s = 1.0f / s;
    }
    __syncthreads();

    {
        int jj = (chunk << 8) + tid;
        const bf16* qvb = qvBb + ((size_t)b * 128) * 1024 + jj;
        float a0 = 0.f;
#pragma unroll 4
        for (int s2 = 0; s2 < 128; ++s2) a0 += ew[s2] * b2f(qvb[(size_t)s2 * 1024]);
        a0 *= inv_s;
        bf16 cb = f2b(a0);
        xin[(size_t)b * 1536 + 512 + jj] = cb;
        featA[(size_t)b * 2048 + 1024 + jj] = cb;
    }
}

// ---------------------------------------------------------------------------
// Decoder LSTM step. Grid 256 blocks x 64 thr; gates x 4 j packed in N-tile.
// h state carried as bf16 (hb_in/hb_out); c state fp32 (cd).
__global__ __launch_bounds__(64) void k_dec_z(const bf16* __restrict__ xin,
                                              const bf16* __restrict__ Wih,
                                              const bf16* __restrict__ hb_in,
                                              const bf16* __restrict__ Whh,
                                              const float* __restrict__ bih,
                                              const float* __restrict__ bhh,
                                              float* __restrict__ cd,
                                              bf16* __restrict__ hb_out,
                                              bf16* __restrict__ featA) {
    __shared__ float zl[32][16];
    int j0 = blockIdx.x * 4;
    int l = threadIdx.x;
    int r = l & 15, ko = (l >> 4) * 8;
    int wrow = (r >> 2) * 1024 + j0 + (r & 3);

    f32x4 acc0 = {0.f, 0.f, 0.f, 0.f}, acc1 = {0.f, 0.f, 0.f, 0.f};
    {
        const bf16* a0 = xin + (size_t)r * 1536 + ko;
        const bf16* a1 = xin + (size_t)(16 + r) * 1536 + ko;
        const bf16* bp = Wih + (size_t)wrow * 1536 + ko;
#pragma unroll 4
        for (int kk = 0; kk < 48; ++kk) {
            bf16x8 bv = ld8(bp + kk * 32);
            acc0 = MFMA(ld8(a0 + kk * 32), bv, acc0);
            acc1 = MFMA(ld8(a1 + kk * 32), bv, acc1);
        }
    }
    {
        const bf16* a0 = hb_in + (size_t)r * 1024 + ko;
        const bf16* a1 = hb_in + (size_t)(16 + r) * 1024 + ko;
        const bf16* bp = Whh + (size_t)wrow * 1024 + ko;
#pragma unroll 4
        for (int kk = 0; kk < 32; ++kk) {
            bf16x8 bv = ld8(bp + kk * 32);
            acc0 = MFMA(ld8(a0 + kk * 32), bv, acc0);
            acc1 = MFMA(ld8(a1 + kk * 32), bv, acc1);
        }
    }
    int ccol = l & 15, cr = (l >> 4) * 4;
#pragma unroll
    for (int q = 0; q < 4; ++q) {
        zl[cr + q][ccol] = acc0[q];
        zl[16 + cr + q][ccol] = acc1[q];
    }
    __syncthreads();

#pragma unroll
    for (int e = l; e < 128; e += 64) {
        int b = e >> 2, jj = e & 3;
        int j = j0 + jj;
        float zi = zl[b][jj]      + bih[j]        + bhh[j];
        float zf = zl[b][4 + jj]  + bih[1024 + j] + bhh[1024 + j];
        float zg = zl[b][8 + jj]  + bih[2048 + j] + bhh[2048 + j];
        float zo = zl[b][12 + jj] + bih[3072 + j] + bhh[3072 + j];
        int hi = b * 1024 + j;
        float co = cd[hi];
        float cn = sigf(zf) * co + sigf(zi) * tanhf(zg);
        float hn = sigf(zo) * tanhf(cn);
        cd[hi] = cn;
        hb_out[hi] = f2b(hn);
        featA[(size_t)b * 2048 + j] = f2b(hn);
    }
}

// ---------------------------------------------------------------------------
extern "C" void kernel_launch(void* const* d_in, const int* in_sizes, int n_in,
                              void* d_out, int out_size, void* d_ws, size_t ws_size,
                              hipStream_t stream) {
    const float* embed   = (const float*)d_in[0];
    const float* enc_Wih = (const float*)d_in[1];
    const float* enc_Whh = (const float*)d_in[2];
    const float* enc_bih = (const float*)d_in[3];
    const float* enc_bhh = (const float*)d_in[4];
    const float* dec_Wih = (const float*)d_in[5];
    const float* dec_Whh = (const float*)d_in[6];
    const float* dec_bih = (const float*)d_in[7];
    const float* dec_bhh = (const float*)d_in[8];
    const float* qk_W    = (const float*)d_in[9];
    const float* qk_b    = (const float*)d_in[10];
    const float* qv_W    = (const float*)d_in[11];
    const float* qv_b    = (const float*)d_in[12];
    const float* ak_W    = (const float*)d_in[13];
    const float* ak_b    = (const float*)d_in[14];
    const float* out_W   = (const float*)d_in[15];
    const float* out_b   = (const float*)d_in[16];
    const float* wd_b    = (const float*)d_in[17];
    const float* hfc1_W  = (const float*)d_in[18];
    const float* hfc1_b  = (const float*)d_in[19];
    const float* hfc2_W  = (const float*)d_in[20];
    const float* hfc2_b  = (const float*)d_in[21];
    const float* cfc1_W  = (const float*)d_in[22];
    const float* cfc1_b  = (const float*)d_in[23];
    const float* cfc2_W  = (const float*)d_in[24];
    const float* cfc2_b  = (const float*)d_in[25];
    const int* src  = (const int*)d_in[26];
    const int* lens = (const int*)d_in[27];
    const int* trg  = (const int*)d_in[28];

    char* cur = (char*)d_ws;
    auto alloc = [&](size_t bytes) -> char* {
        char* p = cur;
        cur += (bytes + 255) & ~(size_t)255;
        return p;
    };
    bf16* embedB  = (bf16*)alloc((size_t)16384000 * 2);
    bf16* encWihB = (bf16*)alloc((size_t)2097152 * 2);
    bf16* encWhhB = (bf16*)alloc((size_t)4194304 * 2);
    bf16* decWihB = (bf16*)alloc((size_t)6291456 * 2);
    bf16* decWhhB = (bf16*)alloc((size_t)4194304 * 2);
    bf16* qkWB    = (bf16*)alloc((size_t)102400 * 2);
    bf16* qvWB    = (bf16*)alloc((size_t)1048576 * 2);
    bf16* outWB   = (bf16*)alloc((size_t)1048576 * 2);
    bf16* hfc1B   = (bf16*)alloc((size_t)2097152 * 2);
    bf16* hfc2B   = (bf16*)alloc((size_t)2097152 * 2);
    bf16* cfc1B   = (bf16*)alloc((size_t)2097152 * 2);
    bf16* cfc2B   = (bf16*)alloc((size_t)2097152 * 2);
    bf16* akWP    = (bf16*)alloc((size_t)112 * 1024 * 2);   // padded ak_W (112 rows)
    bf16*  Xsrc  = (bf16*)alloc((size_t)4096 * 512 * 2);
    bf16*  Zx    = (bf16*)alloc((size_t)4096 * 4096 * 2);
    bf16*  SH    = (bf16*)alloc((size_t)4096 * 1024 * 2);
    float* qkB   = (float*)alloc((size_t)4096 * 100 * 4);
    bf16*  qvBb  = (bf16*)alloc((size_t)4096 * 1024 * 2);   // q_value in bf16
    float* akey  = (float*)alloc((size_t)32 * 112 * 4);
    float* akbP  = (float*)alloc(112 * 4);
    bf16*  hbA   = (bf16*)alloc(32 * 1024 * 2);
    bf16*  hbB   = (bf16*)alloc(32 * 1024 * 2);
    bf16*  cbT   = (bf16*)alloc(32 * 1024 * 2);
    bf16*  t1    = (bf16*)alloc(32 * 2048 * 2);
    float* cd    = (float*)alloc(32 * 1024 * 4);
    bf16*  hdA   = (bf16*)alloc(32 * 1024 * 2);
    bf16*  hdB   = (bf16*)alloc(32 * 1024 * 2);
    bf16*  xin   = (bf16*)alloc(32 * 1536 * 2);
    bf16*  featA = (bf16*)alloc(32 * 2048 * 2);
    bf16*  feats = (bf16*)alloc((size_t)608 * 512 * 2);
    int*   flags = (int*)alloc((size_t)128 * 64 * 4);
    if ((size_t)(cur - (char*)d_ws) > ws_size) return;  // workspace too small

    hipMemsetAsync(hbA, 0, 32 * 1024 * 2, stream);
    hipMemsetAsync(flags, 0, (size_t)128 * 64 * 4, stream);
    hipMemsetAsync(akbP, 0, 112 * 4, stream);
    hipMemcpyAsync(akbP, ak_b, 100 * 4, hipMemcpyDeviceToDevice, stream);

    ConvTable tab;
    tab.d[0]  = {embed,   embedB,  16384000};
    tab.d[1]  = {enc_Wih, encWihB, 2097152};
    tab.d[2]  = {enc_Whh, encWhhB, 4194304};
    tab.d[3]  = {dec_Wih, decWihB, 6291456};
    tab.d[4]  = {dec_Whh, decWhhB, 4194304};
    tab.d[5]  = {qk_W,    qkWB,    102400};
    tab.d[6]  = {qv_W,    qvWB,    1048576};
    tab.d[7]  = {out_W,   outWB,   1048576};
    tab.d[8]  = {hfc1_W,  hfc1B,   2097152};
    tab.d[9]  = {hfc2_W,  hfc2B,   2097152};
    tab.d[10] = {cfc1_W,  cfc1B,   2097152};
    tab.d[11] = {cfc2_W,  cfc2B,   2097152};
    tab.d[12] = {ak_W,    akWP,    102400};   // pad rows 100-111 unread
    k_conv<<<dim3(1024, 13), 256, 0, stream>>>(tab);

    k_gather<<<4096, 256, 0, stream>>>((const unsigned int*)embedB, src, (unsigned int*)Xsrc);

    // Zx = Xsrc @ enc_Wih^T  (M=4096, N=4096, K=512), bf16 out
    k_gemm_bt<<<32 * 32, 256, 0, stream>>>(Xsrc, encWihB, nullptr, nullptr, Zx,
                                           4096, 4096, 512, 4096, 32, 3, 0);

    // Persistent encoder (cooperative launch for co-residency only).
    {
        const bf16* ZxA = Zx;  const bf16* WhhA = encWhhB;
        const float* bihA = enc_bih; const float* bhhA = enc_bhh;
        const int* lensA = lens;
        unsigned int* hb0A = (unsigned int*)hbA;
        unsigned int* hb1A = (unsigned int*)hbB;
        bf16* cbTA = cbT; bf16* SHA = SH; int* flagsA = flags;
        void* args[] = {(void*)&ZxA, (void*)&WhhA, (void*)&bihA, (void*)&bhhA,
                        (void*)&lensA, (void*)&hb0A, (void*)&hb1A, (void*)&cbTA,
                        (void*)&SHA, (void*)&flagsA};
        hipLaunchCooperativeKernel((void*)k_enc_all, dim3(64), dim3(256), args, 0, stream);
    }
    bf16* hbT = hbA;  // publish target at t=127 (odd) is hbw0 == hbA

    k_gemm_sm<<<256, 64, 0, stream>>>(hbT, hfc1B, hfc1_b, nullptr, 0, t1, 2048, 1024, 128, 1);
    k_gemm_sm<<<128, 64, 0, stream>>>(t1, hfc2B, hfc2_b, nullptr, 0, hdA, 1024, 2048, 64, 0);
    k_gemm_sm<<<256, 64, 0, stream>>>(cbT, cfc1B, cfc1_b, nullptr, 0, t1, 2048, 1024, 128, 1);
    k_gemm_sm<<<128, 64, 0, stream>>>(t1, cfc2B, cfc2_b, cd, 1024, nullptr, 0, 2048, 64, 0);

    k_gemm_bt<<<32, 256, 0, stream>>>(SH, qkWB, qk_b, qkB, nullptr,
                                      4096, 100, 1024, 100, 1, 1, 0);
    k_gemm_bt<<<256, 256, 0, stream>>>(SH, qvWB, qv_b, nullptr, qvBb,
                                       4096, 1024, 1024, 1024, 8, 3, 0);

    for (int t = 0; t < 19; ++t) {
        const bf16* hin = (t & 1) ? hdB : hdA;
        bf16* hout = (t & 1) ? hdA : hdB;
        // a_key = tanh(h @ ak_W^T + ak_b): padded 32x112 MFMA GEMM
        k_gemm_sm<<<14, 64, 0, stream>>>(hin, akWP, akbP, akey, 112, nullptr, 0,
                                         1024, 7, 2);
        k_attn<<<128, 256, 0, stream>>>(embedB, trg, akey, qkB, qvBb, lens,
                                        xin, featA, t);
        k_dec_z<<<256, 64, 0, stream>>>(xin, decWihB, hin, decWhhB, dec_bih, dec_bhh,
                                        cd, hout, featA);
        k_gemm_sm<<<64, 64, 0, stream>>>(featA, outWB, out_b, nullptr, 0,
                                         feats + (size_t)t * 32 * 512, 512, 2048, 32, 0);
    }

    // Logits: feats(608x512) @ embed^T(32000x512) + wd_b, XCD-grouped mapping.
    k_gemm_bt<<<1280, 256, 0, stream>>>(feats, embedB, wd_b, (float*)d_out, nullptr,
                                        608, 32000, 512, 0, 250, 2, 1);
}

// Round 10
// 4000.672 us; speedup vs baseline: 1.0861x; 1.0861x over previous
//
#include <hip/hip_runtime.h>
#include <hip/hip_bf16.h>

// Problem constants: B=32, S=128, T=20 (19 dec steps), H=1024, D=512, K_attn=100, V=32000
// Inputs float32; output d_out float32 (B,19,V).
// Encoder: round-9 kernel with ONE change (single-variable experiment):
// ALL flag/data atomics RELAXED (agent scope). Theory: agent-scope atomics
// carry sc1 (LLC-coherent, L2-bypass) per access; the ACQUIRE's buffer_inv
// (L2 invalidate) and RELEASE's buffer_wbl2+vmcnt0 (L2 writeback) are
// redundant and cost ~13us/step (FETCH=103MB shows Zx re-fetched every step).
// Ordering: producer's __syncthreads drains vmcnt (publish stores acked at
// LLC) before the flag RMW; consumer's staging loads issue after spin +
// __syncthreads (compile-time fence) + sched_barrier(0).
// Staging loop byte-identical to round-4/8/9 (rounds 5-7: batched pure-load
// staging deterministically corrupts — do not touch).

using bf16 = __hip_bfloat16;
typedef __attribute__((ext_vector_type(8))) __bf16 bf16x8;
typedef __attribute__((ext_vector_type(4))) float f32x4;

__device__ __forceinline__ bf16x8 ld8(const bf16* p) {
    return *reinterpret_cast<const bf16x8*>(p);
}
__device__ __forceinline__ float b2f(bf16 v) { return __bfloat162float(v); }
__device__ __forceinline__ bf16 f2b(float v) { return __float2bfloat16(v); }
__device__ __forceinline__ unsigned short b2u(bf16 v) {
    unsigned short u; __builtin_memcpy(&u, &v, 2); return u;
}
__device__ __forceinline__ float sigf(float x) { return 1.0f / (1.0f + expf(-x)); }

#define MFMA(a, b, c) __builtin_amdgcn_mfma_f32_16x16x32_bf16((a), (b), (c), 0, 0, 0)

// ---------------------------------------------------------------------------
// f32 -> bf16 conversion for weight tensors. blockIdx.y selects tensor.
struct ConvDesc { const float* src; bf16* dst; int n; };
struct ConvTable { ConvDesc d[13]; };

__global__ __launch_bounds__(256) void k_conv(ConvTable tab) {
    ConvDesc cd = tab.d[blockIdx.y];
    int stride = gridDim.x * blockDim.x * 4;
    for (int i = (blockIdx.x * blockDim.x + threadIdx.x) * 4; i < cd.n; i += stride) {
        float4 v = *reinterpret_cast<const float4*>(cd.src + i);
        bf16 tmp[4] = {f2b(v.x), f2b(v.y), f2b(v.z), f2b(v.w)};
        *reinterpret_cast<ushort4*>(cd.dst + i) = *reinterpret_cast<const ushort4*>(tmp);
    }
}

// ---------------------------------------------------------------------------
// Gather bf16 embedding rows (512 bf16 = 256 u32 per row), one block per row.
__global__ __launch_bounds__(256) void k_gather(const unsigned int* __restrict__ table,
                                                const int* __restrict__ idx,
                                                unsigned int* __restrict__ out) {
    int r = blockIdx.x;
    out[(size_t)r * 256 + threadIdx.x] = table[(size_t)idx[r] * 256 + threadIdx.x];
}

// ---------------------------------------------------------------------------
// Generic big tiled GEMM: C = A(MxK) @ Bw(NxK)^T  (both row-major, bf16)
// mode 0: outF fp32 = C + bias ; mode 1: tanh ; mode 2: logits remap ; mode 3: bf16+bias
// xcdmap=1: group M-tiles of one N-strip consecutively on one XCD (L2 reuse).
__global__ __launch_bounds__(256) void k_gemm_bt(const bf16* __restrict__ A,
                                                 const bf16* __restrict__ Bw,
                                                 const float* __restrict__ bias,
                                                 float* __restrict__ outF,
                                                 bf16* __restrict__ outB,
                                                 int M, int N, int K, int ldo,
                                                 int ntN, int mode, int xcdmap) {
    int bx = blockIdx.x;
    int mt, nt;
    if (xcdmap) {
        int ntM = (M + 127) >> 7;
        int x = bx & 7, w = bx >> 3;
        mt = w % ntM;
        nt = (w / ntM) * 8 + x;
        if (nt >= ntN) return;
    } else {
        mt = bx / ntN;
        nt = bx % ntN;
    }
    int tid = threadIdx.x, wv = tid >> 6, l = tid & 63;
    int m0 = mt * 128 + (wv >> 1) * 64;
    int n0 = nt * 128 + (wv & 1) * 64;
    int r = l & 15, ko = (l >> 4) * 8;

    const bf16* ap[4];
    const bf16* bp[4];
#pragma unroll
    for (int i = 0; i < 4; ++i) {
        int row = m0 + i * 16 + r;
        if (row > M - 1) row = M - 1;
        ap[i] = A + (size_t)row * K + ko;
    }
#pragma unroll
    for (int j = 0; j < 4; ++j) {
        int n = n0 + j * 16 + r;
        if (n > N - 1) n = N - 1;
        bp[j] = Bw + (size_t)n * K + ko;
    }

    f32x4 zv = {0.f, 0.f, 0.f, 0.f};
    f32x4 acc[4][4];
#pragma unroll
    for (int i = 0; i < 4; ++i)
#pragma unroll
        for (int j = 0; j < 4; ++j) acc[i][j] = zv;

    int nk = K >> 5;
    for (int kk = 0; kk < nk; ++kk) {
        bf16x8 af[4], bfv[4];
#pragma unroll
        for (int i = 0; i < 4; ++i) af[i] = ld8(ap[i] + kk * 32);
#pragma unroll
        for (int j = 0; j < 4; ++j) bfv[j] = ld8(bp[j] + kk * 32);
#pragma unroll
        for (int i = 0; i < 4; ++i)
#pragma unroll
            for (int j = 0; j < 4; ++j) acc[i][j] = MFMA(af[i], bfv[j], acc[i][j]);
    }

    int ccol = l & 15, cr = (l >> 4) * 4;
#pragma unroll
    for (int i = 0; i < 4; ++i) {
#pragma unroll
        for (int j = 0; j < 4; ++j) {
            int n = n0 + j * 16 + ccol;
            if (n >= N) continue;
            float bv = bias ? bias[n] : 0.f;
#pragma unroll
            for (int q = 0; q < 4; ++q) {
                int row = m0 + i * 16 + cr + q;
                if (row >= M) continue;
                float v = acc[i][j][q] + bv;
                if (mode == 1) v = tanhf(v);
                if (mode == 2) {
                    outF[((size_t)(row & 31) * 19 + (size_t)(row >> 5)) * 32000 + n] = v;
                } else if (mode == 3) {
                    outB[(size_t)row * ldo + n] = f2b(v);
                } else {
                    outF[(size_t)row * ldo + n] = v;
                }
            }
        }
    }
}

// ---------------------------------------------------------------------------
// Small-M GEMM: one 16x16 tile per block (64 threads = 1 wave).
// act: 0 none, 1 relu, 2 tanh.
__global__ __launch_bounds__(64) void k_gemm_sm(const bf16* __restrict__ A,
                                                const bf16* __restrict__ W,
                                                const float* __restrict__ bias,
                                                float* __restrict__ outF, int ldof,
                                                bf16* __restrict__ outB, int ldob,
                                                int K, int ntN, int act) {
    int bx = blockIdx.x;
    int mt = bx / ntN, nt = bx % ntN;
    int l = threadIdx.x;
    int r = l & 15, ko = (l >> 4) * 8;
    const bf16* ap = A + (size_t)(mt * 16 + r) * K + ko;
    const bf16* bp = W + (size_t)(nt * 16 + r) * K + ko;
    f32x4 acc = {0.f, 0.f, 0.f, 0.f};
    int nk = K >> 5;
#pragma unroll 4
    for (int kk = 0; kk < nk; ++kk) acc = MFMA(ld8(ap + kk * 32), ld8(bp + kk * 32), acc);
    int n = nt * 16 + (l & 15);
    int cr = (l >> 4) * 4;
    float bv = bias ? bias[n] : 0.f;
#pragma unroll
    for (int q = 0; q < 4; ++q) {
        int row = mt * 16 + cr + q;
        float v = acc[q] + bv;
        if (act == 1) v = fmaxf(v, 0.f);
        if (act == 2) v = tanhf(v);
        if (outF) outF[(size_t)row * ldof + n] = v;
        if (outB) outB[(size_t)row * ldob + n] = f2b(v);
    }
}

// ---------------------------------------------------------------------------
// Persistent encoder, 128 LSTM steps. Round-9 kernel; ONLY memory-order
// changes: all agent atomics RELAXED (no buffer_inv / buffer_wbl2 per step).
// Staging loop byte-identical to round 4/8/9.
__global__ __launch_bounds__(256, 1) void k_enc_all(const bf16* __restrict__ Zx,
                                                    const bf16* __restrict__ Whh,
                                                    const float* __restrict__ bih,
                                                    const float* __restrict__ bhh,
                                                    const int* __restrict__ lens,
                                                    unsigned int* __restrict__ hbw0,
                                                    unsigned int* __restrict__ hbw1,
                                                    bf16* __restrict__ cbT,
                                                    bf16* __restrict__ SH,
                                                    int* __restrict__ flags) {
    __shared__ bf16 hlds[32][1024];          // 64KB staged h, XOR-swizzled 16B units
    __shared__ float zl[4][32][16];          // 8KB gate outputs
    __shared__ unsigned short hpub[32][16];  // 1KB publish staging
    unsigned int* hldsw = (unsigned int*)hlds;
    const bf16x8* hldsv = (const bf16x8*)hlds;

    int j0 = blockIdx.x * 16;
    int tid = threadIdx.x;
    int g = tid >> 6, l = tid & 63;
    int r = l & 15, ko = (l >> 4) * 8;

    // Whh slice -> registers (16 rows x 1024 K per wave), loaded once.
    bf16x8 wreg[32];
    {
        const bf16* wp = Whh + (size_t)(g * 1024 + j0 + r) * 1024 + ko;
#pragma unroll
        for (int kk = 0; kk < 32; ++kk) wreg[kk] = ld8(wp + kk * 32);
    }

    int b0 = tid >> 4, ji = tid & 15;
    int b1 = b0 + 16;
    int j = j0 + ji;
    float bs[4];
#pragma unroll
    for (int gg = 0; gg < 4; ++gg) bs[gg] = bih[gg * 1024 + j] + bhh[gg * 1024 + j];
    int len0 = lens[b0], len1 = lens[b1];
    float h0 = 0.f, c0 = 0.f, h1 = 0.f, c1 = 0.f;
    const bf16* zx0 = Zx + (size_t)(b0 * 128) * 4096 + j;
    const bf16* zx1 = Zx + (size_t)(b1 * 128) * 4096 + j;
    int ccol = l & 15, cr = (l >> 4) * 4;
    int rk = r & 7;  // XOR swizzle key (same for rows r and r+16)

    for (int t = 0; t < 128; ++t) {
        // Prefetch Zx[t] (independent of barrier) — hides latency under spin.
        float za0[4], za1[4];
#pragma unroll
        for (int gg = 0; gg < 4; ++gg) {
            za0[gg] = b2f(zx0[(size_t)t * 4096 + gg * 1024]);
            za1[gg] = b2f(zx1[(size_t)t * 4096 + gg * 1024]);
        }

        // Wait for all 64 producers of h_t (t=0: initial zeros from memset).
        // SINGLE CHANGE vs round 9: RELAXED only (no acquire -> no buffer_inv).
        if (t > 0) {
            if (tid < 64) {
                const int* fp = flags + (t - 1) * 64;
                while (true) {
                    int v = __hip_atomic_load(fp + l, __ATOMIC_RELAXED,
                                              __HIP_MEMORY_SCOPE_AGENT);
                    if (__all(v != 0)) break;
                    __builtin_amdgcn_s_sleep(1);
                }
                __builtin_amdgcn_sched_barrier(0);  // pin compile-time order
            }
            __syncthreads();
        }

        // Stage h_t (64KB) LLC -> LDS, swizzled: unit u -> u ^ (row & 7).
        // Byte-identical to round 4/8/9 — DO NOT reschedule (rounds 5-7).
        const unsigned int* hw = (t & 1) ? hbw1 : hbw0;
#pragma unroll 4
        for (int i = 0; i < 64; ++i) {
            int d = i * 256 + tid;
            int b = d >> 9, w = d & 511;
            unsigned int v = __hip_atomic_load(hw + d, __ATOMIC_RELAXED,
                                               __HIP_MEMORY_SCOPE_AGENT);
            hldsw[b * 512 + ((((w >> 2) ^ (b & 7)) << 2) | (w & 3))] = v;
        }
        __syncthreads();

        // z[g] slice = h @ Whh[g-slice]^T from LDS.
        f32x4 acc0 = {0.f, 0.f, 0.f, 0.f}, acc1 = {0.f, 0.f, 0.f, 0.f};
#pragma unroll
        for (int kk = 0; kk < 32; ++kk) {
            int u = kk * 4 + (l >> 4);
            acc0 = MFMA(hldsv[r * 128 + (u ^ rk)], wreg[kk], acc0);
            acc1 = MFMA(hldsv[(16 + r) * 128 + (u ^ rk)], wreg[kk], acc1);
        }
#pragma unroll
        for (int q = 0; q < 4; ++q) {
            zl[g][cr + q][ccol] = acc0[q];
            zl[g][16 + cr + q][ccol] = acc1[q];
        }
        __syncthreads();

        // Fused pointwise: this thread owns (b0,j) and (b1,j).
        {
            float zi = zl[0][b0][ji] + za0[0] + bs[0];
            float zf = zl[1][b0][ji] + za0[1] + bs[1];
            float zg = zl[2][b0][ji] + za0[2] + bs[2];
            float zo = zl[3][b0][ji] + za0[3] + bs[3];
            float cn = sigf(zf) * c0 + sigf(zi) * tanhf(zg);
            float hn = sigf(zo) * tanhf(cn);
            bool msk = t < len0;
            if (msk) { h0 = hn; c0 = cn; }
            hpub[b0][ji] = b2u(f2b(h0));
            SH[((size_t)b0 * 128 + t) * 1024 + j] = msk ? f2b(hn) : f2b(0.f);
        }
        {
            float zi = zl[0][b1][ji] + za1[0] + bs[0];
            float zf = zl[1][b1][ji] + za1[1] + bs[1];
            float zg = zl[2][b1][ji] + za1[2] + bs[2];
            float zo = zl[3][b1][ji] + za1[3] + bs[3];
            float cn = sigf(zf) * c1 + sigf(zi) * tanhf(zg);
            float hn = sigf(zo) * tanhf(cn);
            bool msk = t < len1;
            if (msk) { h1 = hn; c1 = cn; }
            hpub[b1][ji] = b2u(f2b(h1));
            SH[((size_t)b1 * 128 + t) * 1024 + j] = msk ? f2b(hn) : f2b(0.f);
        }
        if (t == 127) {
            cbT[b0 * 1024 + j] = f2b(c0);
            cbT[b1 * 1024 + j] = f2b(c1);
        }
        __syncthreads();

        // Publish this block's h_{t+1} slice (32 b x 16 j = 256 u32) to LLC.
        unsigned int* hwn = (t & 1) ? hbw0 : hbw1;
        {
            int pb = tid >> 3, pw = tid & 7;
            unsigned int val = (unsigned int)hpub[pb][2 * pw] |
                               ((unsigned int)hpub[pb][2 * pw + 1] << 16);
            __hip_atomic_store(hwn + (size_t)pb * 512 + (j0 >> 1) + pw, val,
                               __ATOMIC_RELAXED, __HIP_MEMORY_SCOPE_AGENT);
        }
        __syncthreads();  // vmcnt(0) drain: publish stores acked at LLC
        // SINGLE CHANGE vs round 9: RELAXED RMW (no release -> no buffer_wbl2).
        if (tid == 0)
            __hip_atomic_fetch_add(flags + t * 64 + blockIdx.x, 1, __ATOMIC_RELAXED,
                                   __HIP_MEMORY_SCOPE_AGENT);
    }
}

// ---------------------------------------------------------------------------
// Decoder attention step. Grid 128 = 32 batches x 4 j-chunks (256 cols each).
// a_key precomputed (akey, 32x112 fp32, first 100 valid); qvB in bf16.
__global__ __launch_bounds__(256) void k_attn(const bf16* __restrict__ embedB,
                                              const int* __restrict__ trg,
                                              const float* __restrict__ akey,
                                              const float* __restrict__ qkB,
                                              const bf16* __restrict__ qvBb,
                                              const int* __restrict__ lens,
                                              bf16* __restrict__ xin,
                                              bf16* __restrict__ featA, int t) {
    int b = blockIdx.x >> 2, chunk = blockIdx.x & 3;
    int tid = threadIdx.x;
    if (chunk == 0) {
        const unsigned int* er = (const unsigned int*)(embedB + (size_t)trg[b * 20 + t] * 512);
        ((unsigned int*)(xin + (size_t)b * 1536))[tid] = er[tid];
    }

    __shared__ float ak[100];
    __shared__ float ew[128];
    __shared__ float mxs, inv_s;

    if (tid < 100) ak[tid] = akey[b * 112 + tid];
    __syncthreads();

    if (tid < 128) {
        const float* qr = qkB + ((size_t)b * 128 + tid) * 100;
        float e = 0.f;
#pragma unroll 4
        for (int k = 0; k < 100; ++k) e += qr[k] * ak[k];
        ew[tid] = (tid < lens[b]) ? e : -INFINITY;
    }
    __syncthreads();
    if (tid < 64) {
        float m = fmaxf(ew[tid], ew[tid + 64]);
#pragma unroll
        for (int off = 32; off; off >>= 1) m = fmaxf(m, __shfl_down(m, off));
        if (tid == 0) mxs = m;
    }
    __syncthreads();
    if (tid < 128) ew[tid] = expf(ew[tid] - mxs);  // masked -> 0
    __syncthreads();
    if (tid < 64) {
        float s = ew[tid] + ew[tid + 64];
#pragma unroll
        for (int off = 32; off; off >>= 1) s += __shfl_down(s, off);
        if (tid == 0) inv_s = 1.0f / s;
    }
    __syncthreads();

    {
        int jj = (chunk << 8) + tid;
        const bf16* qvb = qvBb + ((size_t)b * 128) * 1024 + jj;
        float a0 = 0.f;
#pragma unroll 4
        for (int s2 = 0; s2 < 128; ++s2) a0 += ew[s2] * b2f(qvb[(size_t)s2 * 1024]);
        a0 *= inv_s;
        bf16 cb = f2b(a0);
        xin[(size_t)b * 1536 + 512 + jj] = cb;
        featA[(size_t)b * 2048 + 1024 + jj] = cb;
    }
}

// ---------------------------------------------------------------------------
// Decoder LSTM step. Grid 256 blocks x 64 thr; gates x 4 j packed in N-tile.
// h state carried as bf16 (hb_in/hb_out); c state fp32 (cd).
__global__ __launch_bounds__(64) void k_dec_z(const bf16* __restrict__ xin,
                                              const bf16* __restrict__ Wih,
                                              const bf16* __restrict__ hb_in,
                                              const bf16* __restrict__ Whh,
                                              const float* __restrict__ bih,
                                              const float* __restrict__ bhh,
                                              float* __restrict__ cd,
                                              bf16* __restrict__ hb_out,
                                              bf16* __restrict__ featA) {
    __shared__ float zl[32][16];
    int j0 = blockIdx.x * 4;
    int l = threadIdx.x;
    int r = l & 15, ko = (l >> 4) * 8;
    int wrow = (r >> 2) * 1024 + j0 + (r & 3);

    f32x4 acc0 = {0.f, 0.f, 0.f, 0.f}, acc1 = {0.f, 0.f, 0.f, 0.f};
    {
        const bf16* a0 = xin + (size_t)r * 1536 + ko;
        const bf16* a1 = xin + (size_t)(16 + r) * 1536 + ko;
        const bf16* bp = Wih + (size_t)wrow * 1536 + ko;
#pragma unroll 4
        for (int kk = 0; kk < 48; ++kk) {
            bf16x8 bv = ld8(bp + kk * 32);
            acc0 = MFMA(ld8(a0 + kk * 32), bv, acc0);
            acc1 = MFMA(ld8(a1 + kk * 32), bv, acc1);
        }
    }
    {
        const bf16* a0 = hb_in + (size_t)r * 1024 + ko;
        const bf16* a1 = hb_in + (size_t)(16 + r) * 1024 + ko;
        const bf16* bp = Whh + (size_t)wrow * 1024 + ko;
#pragma unroll 4
        for (int kk = 0; kk < 32; ++kk) {
            bf16x8 bv = ld8(bp + kk * 32);
            acc0 = MFMA(ld8(a0 + kk * 32), bv, acc0);
            acc1 = MFMA(ld8(a1 + kk * 32), bv, acc1);
        }
    }
    int ccol = l & 15, cr = (l >> 4) * 4;
#pragma unroll
    for (int q = 0; q < 4; ++q) {
        zl[cr + q][ccol] = acc0[q];
        zl[16 + cr + q][ccol] = acc1[q];
    }
    __syncthreads();

#pragma unroll
    for (int e = l; e < 128; e += 64) {
        int b = e >> 2, jj = e & 3;
        int j = j0 + jj;
        float zi = zl[b][jj]      + bih[j]        + bhh[j];
        float zf = zl[b][4 + jj]  + bih[1024 + j] + bhh[1024 + j];
        float zg = zl[b][8 + jj]  + bih[2048 + j] + bhh[2048 + j];
        float zo = zl[b][12 + jj] + bih[3072 + j] + bhh[3072 + j];
        int hi = b * 1024 + j;
        float co = cd[hi];
        float cn = sigf(zf) * co + sigf(zi) * tanhf(zg);
        float hn = sigf(zo) * tanhf(cn);
        cd[hi] = cn;
        hb_out[hi] = f2b(hn);
        featA[(size_t)b * 2048 + j] = f2b(hn);
    }
}

// ---------------------------------------------------------------------------
extern "C" void kernel_launch(void* const* d_in, const int* in_sizes, int n_in,
                              void* d_out, int out_size, void* d_ws, size_t ws_size,
                              hipStream_t stream) {
    const float* embed   = (const float*)d_in[0];
    const float* enc_Wih = (const float*)d_in[1];
    const float* enc_Whh = (const float*)d_in[2];
    const float* enc_bih = (const float*)d_in[3];
    const float* enc_bhh = (const float*)d_in[4];
    const float* dec_Wih = (const float*)d_in[5];
    const float* dec_Whh = (const float*)d_in[6];
    const float* dec_bih = (const float*)d_in[7];
    const float* dec_bhh = (const float*)d_in[8];
    const float* qk_W    = (const float*)d_in[9];
    const float* qk_b    = (const float*)d_in[10];
    const float* qv_W    = (const float*)d_in[11];
    const float* qv_b    = (const float*)d_in[12];
    const float* ak_W    = (const float*)d_in[13];
    const float* ak_b    = (const float*)d_in[14];
    const float* out_W   = (const float*)d_in[15];
    const float* out_b   = (const float*)d_in[16];
    const float* wd_b    = (const float*)d_in[17];
    const float* hfc1_W  = (const float*)d_in[18];
    const float* hfc1_b  = (const float*)d_in[19];
    const float* hfc2_W  = (const float*)d_in[20];
    const float* hfc2_b  = (const float*)d_in[21];
    const float* cfc1_W  = (const float*)d_in[22];
    const float* cfc1_b  = (const float*)d_in[23];
    const float* cfc2_W  = (const float*)d_in[24];
    const float* cfc2_b  = (const float*)d_in[25];
    const int* src  = (const int*)d_in[26];
    const int* lens = (const int*)d_in[27];
    const int* trg  = (const int*)d_in[28];

    char* cur = (char*)d_ws;
    auto alloc = [&](size_t bytes) -> char* {
        char* p = cur;
        cur += (bytes + 255) & ~(size_t)255;
        return p;
    };
    bf16* embedB  = (bf16*)alloc((size_t)16384000 * 2);
    bf16* encWihB = (bf16*)alloc((size_t)2097152 * 2);
    bf16* encWhhB = (bf16*)alloc((size_t)4194304 * 2);
    bf16* decWihB = (bf16*)alloc((size_t)6291456 * 2);
    bf16* decWhhB = (bf16*)alloc((size_t)4194304 * 2);
    bf16* qkWB    = (bf16*)alloc((size_t)102400 * 2);
    bf16* qvWB    = (bf16*)alloc((size_t)1048576 * 2);
    bf16* outWB   = (bf16*)alloc((size_t)1048576 * 2);
    bf16* hfc1B   = (bf16*)alloc((size_t)2097152 * 2);
    bf16* hfc2B   = (bf16*)alloc((size_t)2097152 * 2);
    bf16* cfc1B   = (bf16*)alloc((size_t)2097152 * 2);
    bf16* cfc2B   = (bf16*)alloc((size_t)2097152 * 2);
    bf16* akWP    = (bf16*)alloc((size_t)112 * 1024 * 2);   // padded ak_W (112 rows)
    bf16*  Xsrc  = (bf16*)alloc((size_t)4096 * 512 * 2);
    bf16*  Zx    = (bf16*)alloc((size_t)4096 * 4096 * 2);
    bf16*  SH    = (bf16*)alloc((size_t)4096 * 1024 * 2);
    float* qkB   = (float*)alloc((size_t)4096 * 100 * 4);
    bf16*  qvBb  = (bf16*)alloc((size_t)4096 * 1024 * 2);   // q_value in bf16
    float* akey  = (float*)alloc((size_t)32 * 112 * 4);
    float* akbP  = (float*)alloc(112 * 4);
    bf16*  hbA   = (bf16*)alloc(32 * 1024 * 2);
    bf16*  hbB   = (bf16*)alloc(32 * 1024 * 2);
    bf16*  cbT   = (bf16*)alloc(32 * 1024 * 2);
    bf16*  t1    = (bf16*)alloc(32 * 2048 * 2);
    float* cd    = (float*)alloc(32 * 1024 * 4);
    bf16*  hdA   = (bf16*)alloc(32 * 1024 * 2);
    bf16*  hdB   = (bf16*)alloc(32 * 1024 * 2);
    bf16*  xin   = (bf16*)alloc(32 * 1536 * 2);
    bf16*  featA = (bf16*)alloc(32 * 2048 * 2);
    bf16*  feats = (bf16*)alloc((size_t)608 * 512 * 2);
    int*   flags = (int*)alloc((size_t)128 * 64 * 4);
    if ((size_t)(cur - (char*)d_ws) > ws_size) return;  // workspace too small

    hipMemsetAsync(hbA, 0, 32 * 1024 * 2, stream);
    hipMemsetAsync(flags, 0, (size_t)128 * 64 * 4, stream);
    hipMemsetAsync(akbP, 0, 112 * 4, stream);
    hipMemcpyAsync(akbP, ak_b, 100 * 4, hipMemcpyDeviceToDevice, stream);

    ConvTable tab;
    tab.d[0]  = {embed,   embedB,  16384000};
    tab.d[1]  = {enc_Wih, encWihB, 2097152};
    tab.d[2]  = {enc_Whh, encWhhB, 4194304};
    tab.d[3]  = {dec_Wih, decWihB, 6291456};
    tab.d[4]  = {dec_Whh, decWhhB, 4194304};
    tab.d[5]  = {qk_W,    qkWB,    102400};
    tab.d[6]  = {qv_W,    qvWB,    1048576};
    tab.d[7]  = {out_W,   outWB,   1048576};
    tab.d[8]  = {hfc1_W,  hfc1B,   2097152};
    tab.d[9]  = {hfc2_W,  hfc2B,   2097152};
    tab.d[10] = {cfc1_W,  cfc1B,   2097152};
    tab.d[11] = {cfc2_W,  cfc2B,   2097152};
    tab.d[12] = {ak_W,    akWP,    102400};   // pad rows 100-111 unread
    k_conv<<<dim3(1024, 13), 256, 0, stream>>>(tab);

    k_gather<<<4096, 256, 0, stream>>>((const unsigned int*)embedB, src, (unsigned int*)Xsrc);

    // Zx = Xsrc @ enc_Wih^T  (M=4096, N=4096, K=512), bf16 out
    k_gemm_bt<<<32 * 32, 256, 0, stream>>>(Xsrc, encWihB, nullptr, nullptr, Zx,
                                           4096, 4096, 512, 4096, 32, 3, 0);

    // Persistent encoder (cooperative launch for co-residency only).
    {
        const bf16* ZxA = Zx;  const bf16* WhhA = encWhhB;
        const float* bihA = enc_bih; const float* bhhA = enc_bhh;
        const int* lensA = lens;
        unsigned int* hb0A = (unsigned int*)hbA;
        unsigned int* hb1A = (unsigned int*)hbB;
        bf16* cbTA = cbT; bf16* SHA = SH; int* flagsA = flags;
        void* args[] = {(void*)&ZxA, (void*)&WhhA, (void*)&bihA, (void*)&bhhA,
                        (void*)&lensA, (void*)&hb0A, (void*)&hb1A, (void*)&cbTA,
                        (void*)&SHA, (void*)&flagsA};
        hipLaunchCooperativeKernel((void*)k_enc_all, dim3(64), dim3(256), args, 0, stream);
    }
    bf16* hbT = hbA;  // publish target at t=127 (odd) is hbw0 == hbA

    k_gemm_sm<<<256, 64, 0, stream>>>(hbT, hfc1B, hfc1_b, nullptr, 0, t1, 2048, 1024, 128, 1);
    k_gemm_sm<<<128, 64, 0, stream>>>(t1, hfc2B, hfc2_b, nullptr, 0, hdA, 1024, 2048, 64, 0);
    k_gemm_sm<<<256, 64, 0, stream>>>(cbT, cfc1B, cfc1_b, nullptr, 0, t1, 2048, 1024, 128, 1);
    k_gemm_sm<<<128, 64, 0, stream>>>(t1, cfc2B, cfc2_b, cd, 1024, nullptr, 0, 2048, 64, 0);

    k_gemm_bt<<<32, 256, 0, stream>>>(SH, qkWB, qk_b, qkB, nullptr,
                                      4096, 100, 1024, 100, 1, 1, 0);
    k_gemm_bt<<<256, 256, 0, stream>>>(SH, qvWB, qv_b, nullptr, qvBb,
                                       4096, 1024, 1024, 1024, 8, 3, 0);

    for (int t = 0; t < 19; ++t) {
        const bf16* hin = (t & 1) ? hdB : hdA;
        bf16* hout = (t & 1) ? hdA : hdB;
        // a_key = tanh(h @ ak_W^T + ak_b): padded 32x112 MFMA GEMM
        k_gemm_sm<<<14, 64, 0, stream>>>(hin, akWP, akbP, akey, 112, nullptr, 0,
                                         1024, 7, 2);
        k_attn<<<128, 256, 0, stream>>>(embedB, trg, akey, qkB, qvBb, lens,
                                        xin, featA, t);
        k_dec_z<<<256, 64, 0, stream>>>(xin, decWihB, hin, decWhhB, dec_bih, dec_bhh,
                                        cd, hout, featA);
        k_gemm_sm<<<64, 64, 0, stream>>>(featA, outWB, out_b, nullptr, 0,
                                         feats + (size_t)t * 32 * 512, 512, 2048, 32, 0);
    }

    // Logits: feats(608x512) @ embed^T(32000x512) + wd_b, XCD-grouped mapping.
    k_gemm_bt<<<1280, 256, 0, stream>>>(feats, embedB, wd_b, (float*)d_out, nullptr,
                                        608, 32000, 512, 0, 250, 2, 1);
}

// Round 13
// 2418.936 us; speedup vs baseline: 1.7962x; 1.6539x over previous
//
#include <hip/hip_runtime.h>
#include <hip/hip_bf16.h>

// Problem constants: B=32, S=128, T=20 (19 dec steps), H=1024, D=512, K_attn=100, V=32000
// Inputs float32; output d_out float32 (B,19,V).
// Encoder (round 13): batch rows are INDEPENDENT recurrences -> partition into
// 4 groups of 8 batches. Grid 256 = 4 groups x 64 j-blocks. Per step each block
// stages only its group's h (16KB, 4x less), polls its group's 64 flags, does
// one M-tile of MFMA. Exchange protocol/primitives are the round-10 PROVEN form
// verbatim (relaxed agent atomics, interleaved one-load-one-write staging with
// unroll 4 — rounds 5/6/7/12 proved every batched staging variant corrupts
// deterministically; DO NOT reschedule the staging loop).

using bf16 = __hip_bfloat16;
typedef __attribute__((ext_vector_type(8))) __bf16 bf16x8;
typedef __attribute__((ext_vector_type(4))) float f32x4;

__device__ __forceinline__ bf16x8 ld8(const bf16* p) {
    return *reinterpret_cast<const bf16x8*>(p);
}
__device__ __forceinline__ float b2f(bf16 v) { return __bfloat162float(v); }
__device__ __forceinline__ bf16 f2b(float v) { return __float2bfloat16(v); }
__device__ __forceinline__ unsigned short b2u(bf16 v) {
    unsigned short u; __builtin_memcpy(&u, &v, 2); return u;
}
__device__ __forceinline__ float sigf(float x) { return 1.0f / (1.0f + expf(-x)); }

#define MFMA(a, b, c) __builtin_amdgcn_mfma_f32_16x16x32_bf16((a), (b), (c), 0, 0, 0)

// ---------------------------------------------------------------------------
// f32 -> bf16 conversion for weight tensors. blockIdx.y selects tensor.
struct ConvDesc { const float* src; bf16* dst; int n; };
struct ConvTable { ConvDesc d[13]; };

__global__ __launch_bounds__(256) void k_conv(ConvTable tab) {
    ConvDesc cd = tab.d[blockIdx.y];
    int stride = gridDim.x * blockDim.x * 4;
    for (int i = (blockIdx.x * blockDim.x + threadIdx.x) * 4; i < cd.n; i += stride) {
        float4 v = *reinterpret_cast<const float4*>(cd.src + i);
        bf16 tmp[4] = {f2b(v.x), f2b(v.y), f2b(v.z), f2b(v.w)};
        *reinterpret_cast<ushort4*>(cd.dst + i) = *reinterpret_cast<const ushort4*>(tmp);
    }
}

// ---------------------------------------------------------------------------
// Gather bf16 embedding rows (512 bf16 = 256 u32 per row), one block per row.
__global__ __launch_bounds__(256) void k_gather(const unsigned int* __restrict__ table,
                                                const int* __restrict__ idx,
                                                unsigned int* __restrict__ out) {
    int r = blockIdx.x;
    out[(size_t)r * 256 + threadIdx.x] = table[(size_t)idx[r] * 256 + threadIdx.x];
}

// ---------------------------------------------------------------------------
// Generic big tiled GEMM: C = A(MxK) @ Bw(NxK)^T  (both row-major, bf16)
// mode 0: outF fp32 = C + bias ; mode 1: tanh ; mode 2: logits remap ; mode 3: bf16+bias
// xcdmap=1: group M-tiles of one N-strip consecutively on one XCD (L2 reuse).
__global__ __launch_bounds__(256) void k_gemm_bt(const bf16* __restrict__ A,
                                                 const bf16* __restrict__ Bw,
                                                 const float* __restrict__ bias,
                                                 float* __restrict__ outF,
                                                 bf16* __restrict__ outB,
                                                 int M, int N, int K, int ldo,
                                                 int ntN, int mode, int xcdmap) {
    int bx = blockIdx.x;
    int mt, nt;
    if (xcdmap) {
        int ntM = (M + 127) >> 7;
        int x = bx & 7, w = bx >> 3;
        mt = w % ntM;
        nt = (w / ntM) * 8 + x;
        if (nt >= ntN) return;
    } else {
        mt = bx / ntN;
        nt = bx % ntN;
    }
    int tid = threadIdx.x, wv = tid >> 6, l = tid & 63;
    int m0 = mt * 128 + (wv >> 1) * 64;
    int n0 = nt * 128 + (wv & 1) * 64;
    int r = l & 15, ko = (l >> 4) * 8;

    const bf16* ap[4];
    const bf16* bp[4];
#pragma unroll
    for (int i = 0; i < 4; ++i) {
        int row = m0 + i * 16 + r;
        if (row > M - 1) row = M - 1;
        ap[i] = A + (size_t)row * K + ko;
    }
#pragma unroll
    for (int j = 0; j < 4; ++j) {
        int n = n0 + j * 16 + r;
        if (n > N - 1) n = N - 1;
        bp[j] = Bw + (size_t)n * K + ko;
    }

    f32x4 zv = {0.f, 0.f, 0.f, 0.f};
    f32x4 acc[4][4];
#pragma unroll
    for (int i = 0; i < 4; ++i)
#pragma unroll
        for (int j = 0; j < 4; ++j) acc[i][j] = zv;

    int nk = K >> 5;
    for (int kk = 0; kk < nk; ++kk) {
        bf16x8 af[4], bfv[4];
#pragma unroll
        for (int i = 0; i < 4; ++i) af[i] = ld8(ap[i] + kk * 32);
#pragma unroll
        for (int j = 0; j < 4; ++j) bfv[j] = ld8(bp[j] + kk * 32);
#pragma unroll
        for (int i = 0; i < 4; ++i)
#pragma unroll
            for (int j = 0; j < 4; ++j) acc[i][j] = MFMA(af[i], bfv[j], acc[i][j]);
    }

    int ccol = l & 15, cr = (l >> 4) * 4;
#pragma unroll
    for (int i = 0; i < 4; ++i) {
#pragma unroll
        for (int j = 0; j < 4; ++j) {
            int n = n0 + j * 16 + ccol;
            if (n >= N) continue;
            float bv = bias ? bias[n] : 0.f;
#pragma unroll
            for (int q = 0; q < 4; ++q) {
                int row = m0 + i * 16 + cr + q;
                if (row >= M) continue;
                float v = acc[i][j][q] + bv;
                if (mode == 1) v = tanhf(v);
                if (mode == 2) {
                    outF[((size_t)(row & 31) * 19 + (size_t)(row >> 5)) * 32000 + n] = v;
                } else if (mode == 3) {
                    outB[(size_t)row * ldo + n] = f2b(v);
                } else {
                    outF[(size_t)row * ldo + n] = v;
                }
            }
        }
    }
}

// ---------------------------------------------------------------------------
// Small-M GEMM: one 16x16 tile per block (64 threads = 1 wave).
// act: 0 none, 1 relu, 2 tanh.
__global__ __launch_bounds__(64) void k_gemm_sm(const bf16* __restrict__ A,
                                                const bf16* __restrict__ W,
                                                const float* __restrict__ bias,
                                                float* __restrict__ outF, int ldof,
                                                bf16* __restrict__ outB, int ldob,
                                                int K, int ntN, int act) {
    int bx = blockIdx.x;
    int mt = bx / ntN, nt = bx % ntN;
    int l = threadIdx.x;
    int r = l & 15, ko = (l >> 4) * 8;
    const bf16* ap = A + (size_t)(mt * 16 + r) * K + ko;
    const bf16* bp = W + (size_t)(nt * 16 + r) * K + ko;
    f32x4 acc = {0.f, 0.f, 0.f, 0.f};
    int nk = K >> 5;
#pragma unroll 4
    for (int kk = 0; kk < nk; ++kk) acc = MFMA(ld8(ap + kk * 32), ld8(bp + kk * 32), acc);
    int n = nt * 16 + (l & 15);
    int cr = (l >> 4) * 4;
    float bv = bias ? bias[n] : 0.f;
#pragma unroll
    for (int q = 0; q < 4; ++q) {
        int row = mt * 16 + cr + q;
        float v = acc[q] + bv;
        if (act == 1) v = fmaxf(v, 0.f);
        if (act == 2) v = tanhf(v);
        if (outF) outF[(size_t)row * ldof + n] = v;
        if (outB) outB[(size_t)row * ldob + n] = f2b(v);
    }
}

// ---------------------------------------------------------------------------
// Persistent encoder, 128 LSTM steps. Grid 256 = 4 batch-groups x 64 j-blocks.
// Each block: gate-per-wave, j-slice of 16 (Whh rows in registers), its group's
// 8 batches. Exchange = round-10 proven protocol, 4x smaller volume.
__global__ __launch_bounds__(256, 1) void k_enc_all(const bf16* __restrict__ Zx,
                                                    const bf16* __restrict__ Whh,
                                                    const float* __restrict__ bih,
                                                    const float* __restrict__ bhh,
                                                    const int* __restrict__ lens,
                                                    unsigned int* __restrict__ hbw0,
                                                    unsigned int* __restrict__ hbw1,
                                                    bf16* __restrict__ cbT,
                                                    bf16* __restrict__ SH,
                                                    int* __restrict__ flags) {
    __shared__ bf16 hlds[8][1024];           // 16KB staged group h, swizzled 16B units
    __shared__ float zl[4][8][16];           // 2KB gate outputs
    __shared__ unsigned short hpub[8][16];   // publish staging
    unsigned int* hldsw = (unsigned int*)hlds;
    const bf16x8* hldsv = (const bf16x8*)hlds;

    int bid = blockIdx.x;
    int grp = bid >> 6, jblk = bid & 63;
    int j0 = jblk * 16;
    int tid = threadIdx.x;
    int g = tid >> 6, l = tid & 63;
    int r = l & 15, ko = (l >> 4) * 8;

    // Whh slice -> registers (16 rows x 1024 K per wave), loaded once.
    bf16x8 wreg[32];
    {
        const bf16* wp = Whh + (size_t)(g * 1024 + j0 + r) * 1024 + ko;
#pragma unroll
        for (int kk = 0; kk < 32; ++kk) wreg[kk] = ld8(wp + kk * 32);
    }

    // Pointwise ownership (tid < 128): one (batch, j) element.
    int bl = tid >> 4, ji = tid & 15;   // bl in [0,8) for tid<128
    int b = grp * 8 + bl;
    int j = j0 + ji;
    bool pw = tid < 128;
    float bs[4] = {0.f, 0.f, 0.f, 0.f};
    int lenv = 0;
    float hs = 0.f, cs = 0.f;
    const bf16* zxp = Zx;
    if (pw) {
#pragma unroll
        for (int gg = 0; gg < 4; ++gg) bs[gg] = bih[gg * 1024 + j] + bhh[gg * 1024 + j];
        lenv = lens[b];
        zxp = Zx + (size_t)(b * 128) * 4096 + j;
    }
    int ccol = l & 15, cr = (l >> 4) * 4;
    int rk = r & 7;                       // XOR swizzle key (row & 7)
    unsigned int gbase = grp * 4096;      // group's u32 offset into h buffers

    for (int t = 0; t < 128; ++t) {
        // Prefetch Zx[t] (independent of barrier) — hides latency under spin.
        float za[4] = {0.f, 0.f, 0.f, 0.f};
        if (pw) {
#pragma unroll
            for (int gg = 0; gg < 4; ++gg)
                za[gg] = b2f(zxp[(size_t)t * 4096 + gg * 1024]);
        }

        // Wait for this group's 64 producers of h_t (t=0: initial zeros).
        if (t > 0) {
            if (tid < 64) {
                const int* fp = flags + (t - 1) * 256 + grp * 64;
                while (true) {
                    int v = __hip_atomic_load(fp + l, __ATOMIC_RELAXED,
                                              __HIP_MEMORY_SCOPE_AGENT);
                    if (__all(v != 0)) break;
                    __builtin_amdgcn_s_sleep(1);
                }
                __builtin_amdgcn_sched_barrier(0);  // pin compile-time order
            }
            __syncthreads();
        }

        // Stage group h_t (4096 u32) LLC -> LDS, swizzled: unit u -> u^(row&7).
        // PROVEN interleaved form (unroll 4, one load one write) — DO NOT
        // reschedule (rounds 5/6/7/12 all corrupted deterministically).
        const unsigned int* hw = ((t & 1) ? hbw1 : hbw0) + gbase;
#pragma unroll 4
        for (int i = 0; i < 16; ++i) {
            int d = i * 256 + tid;
            int bb = d >> 9, w = d & 511;
            unsigned int v = __hip_atomic_load(hw + d, __ATOMIC_RELAXED,
                                               __HIP_MEMORY_SCOPE_AGENT);
            hldsw[bb * 512 + ((((w >> 2) ^ (bb & 7)) << 2) | (w & 3))] = v;
        }
        __syncthreads();

        // z[g] slice = h @ Whh[g-slice]^T from LDS. Only 8 valid M rows;
        // lanes with (l&15)>=8 read aliased rows (results discarded — matmul
        // rows are independent).
        f32x4 acc0 = {0.f, 0.f, 0.f, 0.f};
#pragma unroll
        for (int kk = 0; kk < 32; ++kk) {
            int u = kk * 4 + (l >> 4);
            acc0 = MFMA(hldsv[(r & 7) * 128 + (u ^ rk)], wreg[kk], acc0);
        }
        if (l < 32) {
#pragma unroll
            for (int q = 0; q < 4; ++q) zl[g][cr + q][ccol] = acc0[q];
        }
        __syncthreads();

        // Fused pointwise: one (b, j) element per thread (tid < 128).
        if (pw) {
            float zi = zl[0][bl][ji] + za[0] + bs[0];
            float zf = zl[1][bl][ji] + za[1] + bs[1];
            float zg = zl[2][bl][ji] + za[2] + bs[2];
            float zo = zl[3][bl][ji] + za[3] + bs[3];
            float cn = sigf(zf) * cs + sigf(zi) * tanhf(zg);
            float hn = sigf(zo) * tanhf(cn);
            bool msk = t < lenv;
            if (msk) { hs = hn; cs = cn; }
            hpub[bl][ji] = b2u(f2b(hs));
            SH[((size_t)b * 128 + t) * 1024 + j] = msk ? f2b(hn) : f2b(0.f);
            if (t == 127) cbT[b * 1024 + j] = f2b(cs);
        }
        __syncthreads();

        // Publish this block's h_{t+1} slice (8 b x 16 j = 64 u32) to LLC.
        unsigned int* hwn = ((t & 1) ? hbw0 : hbw1) + gbase;
        if (tid < 64) {
            int pb = tid >> 3, pq = tid & 7;
            unsigned int val = (unsigned int)hpub[pb][2 * pq] |
                               ((unsigned int)hpub[pb][2 * pq + 1] << 16);
            __hip_atomic_store(hwn + (size_t)pb * 512 + (j0 >> 1) + pq, val,
                               __ATOMIC_RELAXED, __HIP_MEMORY_SCOPE_AGENT);
        }
        __syncthreads();  // vmcnt(0) drain: publish stores acked at LLC
        if (tid == 0)
            __hip_atomic_fetch_add(flags + t * 256 + grp * 64 + jblk, 1,
                                   __ATOMIC_RELAXED, __HIP_MEMORY_SCOPE_AGENT);
    }
}

// ---------------------------------------------------------------------------
// Decoder attention step. Grid 128 = 32 batches x 4 j-chunks (256 cols each).
// a_key precomputed (akey, 32x112 fp32, first 100 valid); qvB in bf16.
__global__ __launch_bounds__(256) void k_attn(const bf16* __restrict__ embedB,
                                              const int* __restrict__ trg,
                                              const float* __restrict__ akey,
                                              const float* __restrict__ qkB,
                                              const bf16* __restrict__ qvBb,
                                              const int* __restrict__ lens,
                                              bf16* __restrict__ xin,
                                              bf16* __restrict__ featA, int t) {
    int b = blockIdx.x >> 2, chunk = blockIdx.x & 3;
    int tid = threadIdx.x;
    if (chunk == 0) {
        const unsigned int* er = (const unsigned int*)(embedB + (size_t)trg[b * 20 + t] * 512);
        ((unsigned int*)(xin + (size_t)b * 1536))[tid] = er[tid];
    }

    __shared__ float ak[100];
    __shared__ float ew[128];
    __shared__ float mxs, inv_s;

    if (tid < 100) ak[tid] = akey[b * 112 + tid];
    __syncthreads();

    if (tid < 128) {
        const float* qr = qkB + ((size_t)b * 128 + tid) * 100;
        float e = 0.f;
#pragma unroll 4
        for (int k = 0; k < 100; ++k) e += qr[k] * ak[k];
        ew[tid] = (tid < lens[b]) ? e : -INFINITY;
    }
    __syncthreads();
    if (tid < 64) {
        float m = fmaxf(ew[tid], ew[tid + 64]);
#pragma unroll
        for (int off = 32; off; off >>= 1) m = fmaxf(m, __shfl_down(m, off));
        if (tid == 0) mxs = m;
    }
    __syncthreads();
    if (tid < 128) ew[tid] = expf(ew[tid] - mxs);  // masked -> 0
    __syncthreads();
    if (tid < 64) {
        float s = ew[tid] + ew[tid + 64];
#pragma unroll
        for (int off = 32; off; off >>= 1) s += __shfl_down(s, off);
        if (tid == 0) inv_s = 1.0f / s;
    }
    __syncthreads();

    {
        int jj = (chunk << 8) + tid;
        const bf16* qvb = qvBb + ((size_t)b * 128) * 1024 + jj;
        float a0 = 0.f;
#pragma unroll 4
        for (int s2 = 0; s2 < 128; ++s2) a0 += ew[s2] * b2f(qvb[(size_t)s2 * 1024]);
        a0 *= inv_s;
        bf16 cb = f2b(a0);
        xin[(size_t)b * 1536 + 512 + jj] = cb;
        featA[(size_t)b * 2048 + 1024 + jj] = cb;
    }
}

// ---------------------------------------------------------------------------
// Decoder LSTM step. Grid 256 blocks x 64 thr; gates x 4 j packed in N-tile.
// h state carried as bf16 (hb_in/hb_out); c state fp32 (cd).
__global__ __launch_bounds__(64) void k_dec_z(const bf16* __restrict__ xin,
                                              const bf16* __restrict__ Wih,
                                              const bf16* __restrict__ hb_in,
                                              const bf16* __restrict__ Whh,
                                              const float* __restrict__ bih,
                                              const float* __restrict__ bhh,
                                              float* __restrict__ cd,
                                              bf16* __restrict__ hb_out,
                                              bf16* __restrict__ featA) {
    __shared__ float zl[32][16];
    int j0 = blockIdx.x * 4;
    int l = threadIdx.x;
    int r = l & 15, ko = (l >> 4) * 8;
    int wrow = (r >> 2) * 1024 + j0 + (r & 3);

    f32x4 acc0 = {0.f, 0.f, 0.f, 0.f}, acc1 = {0.f, 0.f, 0.f, 0.f};
    {
        const bf16* a0 = xin + (size_t)r * 1536 + ko;
        const bf16* a1 = xin + (size_t)(16 + r) * 1536 + ko;
        const bf16* bp = Wih + (size_t)wrow * 1536 + ko;
#pragma unroll 4
        for (int kk = 0; kk < 48; ++kk) {
            bf16x8 bv = ld8(bp + kk * 32);
            acc0 = MFMA(ld8(a0 + kk * 32), bv, acc0);
            acc1 = MFMA(ld8(a1 + kk * 32), bv, acc1);
        }
    }
    {
        const bf16* a0 = hb_in + (size_t)r * 1024 + ko;
        const bf16* a1 = hb_in + (size_t)(16 + r) * 1024 + ko;
        const bf16* bp = Whh + (size_t)wrow * 1024 + ko;
#pragma unroll 4
        for (int kk = 0; kk < 32; ++kk) {
            bf16x8 bv = ld8(bp + kk * 32);
            acc0 = MFMA(ld8(a0 + kk * 32), bv, acc0);
            acc1 = MFMA(ld8(a1 + kk * 32), bv, acc1);
        }
    }
    int ccol = l & 15, cr = (l >> 4) * 4;
#pragma unroll
    for (int q = 0; q < 4; ++q) {
        zl[cr + q][ccol] = acc0[q];
        zl[16 + cr + q][ccol] = acc1[q];
    }
    __syncthreads();

#pragma unroll
    for (int e = l; e < 128; e += 64) {
        int b = e >> 2, jj = e & 3;
        int j = j0 + jj;
        float zi = zl[b][jj]      + bih[j]        + bhh[j];
        float zf = zl[b][4 + jj]  + bih[1024 + j] + bhh[1024 + j];
        float zg = zl[b][8 + jj]  + bih[2048 + j] + bhh[2048 + j];
        float zo = zl[b][12 + jj] + bih[3072 + j] + bhh[3072 + j];
        int hi = b * 1024 + j;
        float co = cd[hi];
        float cn = sigf(zf) * co + sigf(zi) * tanhf(zg);
        float hn = sigf(zo) * tanhf(cn);
        cd[hi] = cn;
        hb_out[hi] = f2b(hn);
        featA[(size_t)b * 2048 + j] = f2b(hn);
    }
}

// ---------------------------------------------------------------------------
extern "C" void kernel_launch(void* const* d_in, const int* in_sizes, int n_in,
                              void* d_out, int out_size, void* d_ws, size_t ws_size,
                              hipStream_t stream) {
    const float* embed   = (const float*)d_in[0];
    const float* enc_Wih = (const float*)d_in[1];
    const float* enc_Whh = (const float*)d_in[2];
    const float* enc_bih = (const float*)d_in[3];
    const float* enc_bhh = (const float*)d_in[4];
    const float* dec_Wih = (const float*)d_in[5];
    const float* dec_Whh = (const float*)d_in[6];
    const float* dec_bih = (const float*)d_in[7];
    const float* dec_bhh = (const float*)d_in[8];
    const float* qk_W    = (const float*)d_in[9];
    const float* qk_b    = (const float*)d_in[10];
    const float* qv_W    = (const float*)d_in[11];
    const float* qv_b    = (const float*)d_in[12];
    const float* ak_W    = (const float*)d_in[13];
    const float* ak_b    = (const float*)d_in[14];
    const float* out_W   = (const float*)d_in[15];
    const float* out_b   = (const float*)d_in[16];
    const float* wd_b    = (const float*)d_in[17];
    const float* hfc1_W  = (const float*)d_in[18];
    const float* hfc1_b  = (const float*)d_in[19];
    const float* hfc2_W  = (const float*)d_in[20];
    const float* hfc2_b  = (const float*)d_in[21];
    const float* cfc1_W  = (const float*)d_in[22];
    const float* cfc1_b  = (const float*)d_in[23];
    const float* cfc2_W  = (const float*)d_in[24];
    const float* cfc2_b  = (const float*)d_in[25];
    const int* src  = (const int*)d_in[26];
    const int* lens = (const int*)d_in[27];
    const int* trg  = (const int*)d_in[28];

    char* cur = (char*)d_ws;
    auto alloc = [&](size_t bytes) -> char* {
        char* p = cur;
        cur += (bytes + 255) & ~(size_t)255;
        return p;
    };
    bf16* embedB  = (bf16*)alloc((size_t)16384000 * 2);
    bf16* encWihB = (bf16*)alloc((size_t)2097152 * 2);
    bf16* encWhhB = (bf16*)alloc((size_t)4194304 * 2);
    bf16* decWihB = (bf16*)alloc((size_t)6291456 * 2);
    bf16* decWhhB = (bf16*)alloc((size_t)4194304 * 2);
    bf16* qkWB    = (bf16*)alloc((size_t)102400 * 2);
    bf16* qvWB    = (bf16*)alloc((size_t)1048576 * 2);
    bf16* outWB   = (bf16*)alloc((size_t)1048576 * 2);
    bf16* hfc1B   = (bf16*)alloc((size_t)2097152 * 2);
    bf16* hfc2B   = (bf16*)alloc((size_t)2097152 * 2);
    bf16* cfc1B   = (bf16*)alloc((size_t)2097152 * 2);
    bf16* cfc2B   = (bf16*)alloc((size_t)2097152 * 2);
    bf16* akWP    = (bf16*)alloc((size_t)112 * 1024 * 2);   // padded ak_W (112 rows)
    bf16*  Xsrc  = (bf16*)alloc((size_t)4096 * 512 * 2);
    bf16*  Zx    = (bf16*)alloc((size_t)4096 * 4096 * 2);
    bf16*  SH    = (bf16*)alloc((size_t)4096 * 1024 * 2);
    float* qkB   = (float*)alloc((size_t)4096 * 100 * 4);
    bf16*  qvBb  = (bf16*)alloc((size_t)4096 * 1024 * 2);   // q_value in bf16
    float* akey  = (float*)alloc((size_t)32 * 112 * 4);
    float* akbP  = (float*)alloc(112 * 4);
    bf16*  hbA   = (bf16*)alloc(32 * 1024 * 2);
    bf16*  hbB   = (bf16*)alloc(32 * 1024 * 2);
    bf16*  cbT   = (bf16*)alloc(32 * 1024 * 2);
    bf16*  t1    = (bf16*)alloc(32 * 2048 * 2);
    float* cd    = (float*)alloc(32 * 1024 * 4);
    bf16*  hdA   = (bf16*)alloc(32 * 1024 * 2);
    bf16*  hdB   = (bf16*)alloc(32 * 1024 * 2);
    bf16*  xin   = (bf16*)alloc(32 * 1536 * 2);
    bf16*  featA = (bf16*)alloc(32 * 2048 * 2);
    bf16*  feats = (bf16*)alloc((size_t)608 * 512 * 2);
    int*   flags = (int*)alloc((size_t)128 * 256 * 4);
    if ((size_t)(cur - (char*)d_ws) > ws_size) return;  // workspace too small

    hipMemsetAsync(hbA, 0, 32 * 1024 * 2, stream);
    hipMemsetAsync(flags, 0, (size_t)128 * 256 * 4, stream);
    hipMemsetAsync(akbP, 0, 112 * 4, stream);
    hipMemcpyAsync(akbP, ak_b, 100 * 4, hipMemcpyDeviceToDevice, stream);

    ConvTable tab;
    tab.d[0]  = {embed,   embedB,  16384000};
    tab.d[1]  = {enc_Wih, encWihB, 2097152};
    tab.d[2]  = {enc_Whh, encWhhB, 4194304};
    tab.d[3]  = {dec_Wih, decWihB, 6291456};
    tab.d[4]  = {dec_Whh, decWhhB, 4194304};
    tab.d[5]  = {qk_W,    qkWB,    102400};
    tab.d[6]  = {qv_W,    qvWB,    1048576};
    tab.d[7]  = {out_W,   outWB,   1048576};
    tab.d[8]  = {hfc1_W,  hfc1B,   2097152};
    tab.d[9]  = {hfc2_W,  hfc2B,   2097152};
    tab.d[10] = {cfc1_W,  cfc1B,   2097152};
    tab.d[11] = {cfc2_W,  cfc2B,   2097152};
    tab.d[12] = {ak_W,    akWP,    102400};   // pad rows 100-111 unread
    k_conv<<<dim3(1024, 13), 256, 0, stream>>>(tab);

    k_gather<<<4096, 256, 0, stream>>>((const unsigned int*)embedB, src, (unsigned int*)Xsrc);

    // Zx = Xsrc @ enc_Wih^T  (M=4096, N=4096, K=512), bf16 out
    k_gemm_bt<<<32 * 32, 256, 0, stream>>>(Xsrc, encWihB, nullptr, nullptr, Zx,
                                           4096, 4096, 512, 4096, 32, 3, 0);

    // Persistent encoder (cooperative launch for co-residency only).
    {
        const bf16* ZxA = Zx;  const bf16* WhhA = encWhhB;
        const float* bihA = enc_bih; const float* bhhA = enc_bhh;
        const int* lensA = lens;
        unsigned int* hb0A = (unsigned int*)hbA;
        unsigned int* hb1A = (unsigned int*)hbB;
        bf16* cbTA = cbT; bf16* SHA = SH; int* flagsA = flags;
        void* args[] = {(void*)&ZxA, (void*)&WhhA, (void*)&bihA, (void*)&bhhA,
                        (void*)&lensA, (void*)&hb0A, (void*)&hb1A, (void*)&cbTA,
                        (void*)&SHA, (void*)&flagsA};
        hipLaunchCooperativeKernel((void*)k_enc_all, dim3(256), dim3(256), args, 0, stream);
    }
    bf16* hbT = hbA;  // publish target at t=127 (odd) is hbw0 == hbA

    k_gemm_sm<<<256, 64, 0, stream>>>(hbT, hfc1B, hfc1_b, nullptr, 0, t1, 2048, 1024, 128, 1);
    k_gemm_sm<<<128, 64, 0, stream>>>(t1, hfc2B, hfc2_b, nullptr, 0, hdA, 1024, 2048, 64, 0);
    k_gemm_sm<<<256, 64, 0, stream>>>(cbT, cfc1B, cfc1_b, nullptr, 0, t1, 2048, 1024, 128, 1);
    k_gemm_sm<<<128, 64, 0, stream>>>(t1, cfc2B, cfc2_b, cd, 1024, nullptr, 0, 2048, 64, 0);

    k_gemm_bt<<<32, 256, 0, stream>>>(SH, qkWB, qk_b, qkB, nullptr,
                                      4096, 100, 1024, 100, 1, 1, 0);
    k_gemm_bt<<<256, 256, 0, stream>>>(SH, qvWB, qv_b, nullptr, qvBb,
                                       4096, 1024, 1024, 1024, 8, 3, 0);

    for (int t = 0; t < 19; ++t) {
        const bf16* hin = (t & 1) ? hdB : hdA;
        bf16* hout = (t & 1) ? hdA : hdB;
        // a_key = tanh(h @ ak_W^T + ak_b): padded 32x112 MFMA GEMM
        k_gemm_sm<<<14, 64, 0, stream>>>(hin, akWP, akbP, akey, 112, nullptr, 0,
                                         1024, 7, 2);
        k_attn<<<128, 256, 0, stream>>>(embedB, trg, akey, qkB, qvBb, lens,
                                        xin, featA, t);
        k_dec_z<<<256, 64, 0, stream>>>(xin, decWihB, hin, decWhhB, dec_bih, dec_bhh,
                                        cd, hout, featA);
        k_gemm_sm<<<64, 64, 0, stream>>>(featA, outWB, out_b, nullptr, 0,
                                         feats + (size_t)t * 32 * 512, 512, 2048, 32, 0);
    }

    // Logits: feats(608x512) @ embed^T(32000x512) + wd_b, XCD-grouped mapping.
    k_gemm_bt<<<1280, 256, 0, stream>>>(feats, embedB, wd_b, (float*)d_out, nullptr,
                                        608, 32000, 512, 0, 250, 2, 1);
}

// Round 15
// 2157.954 us; speedup vs baseline: 2.0135x; 1.1209x over previous
//
#include <hip/hip_runtime.h>
#include <hip/hip_bf16.h>

// Problem constants: B=32, S=128, T=20 (19 dec steps), H=1024, D=512, K_attn=100, V=32000
// Inputs float32; output d_out float32 (B,19,V).
// Encoder: round-13 kernel VERBATIM (passing, 734us). 4 batch-groups x 64
// j-blocks; staging via the proven interleaved atomic-load form. Five failed
// variants (rounds 5/6/7/12/14) all corrupted deterministically — the
// exchange structure is FROZEN at this version.
// Decoder: a_key fused into k_attn; out-GEMM deferred to one batched GEMM
// (both exonerated by round-14's bit-identical-failure analysis).

using bf16 = __hip_bfloat16;
typedef __attribute__((ext_vector_type(8))) __bf16 bf16x8;
typedef __attribute__((ext_vector_type(4))) float f32x4;

__device__ __forceinline__ bf16x8 ld8(const bf16* p) {
    return *reinterpret_cast<const bf16x8*>(p);
}
__device__ __forceinline__ float b2f(bf16 v) { return __bfloat162float(v); }
__device__ __forceinline__ bf16 f2b(float v) { return __float2bfloat16(v); }
__device__ __forceinline__ unsigned short b2u(bf16 v) {
    unsigned short u; __builtin_memcpy(&u, &v, 2); return u;
}
__device__ __forceinline__ float sigf(float x) { return 1.0f / (1.0f + expf(-x)); }

#define MFMA(a, b, c) __builtin_amdgcn_mfma_f32_16x16x32_bf16((a), (b), (c), 0, 0, 0)

// ---------------------------------------------------------------------------
// f32 -> bf16 conversion for weight tensors. blockIdx.y selects tensor.
struct ConvDesc { const float* src; bf16* dst; int n; };
struct ConvTable { ConvDesc d[13]; };

__global__ __launch_bounds__(256) void k_conv(ConvTable tab) {
    ConvDesc cd = tab.d[blockIdx.y];
    int stride = gridDim.x * blockDim.x * 4;
    for (int i = (blockIdx.x * blockDim.x + threadIdx.x) * 4; i < cd.n; i += stride) {
        float4 v = *reinterpret_cast<const float4*>(cd.src + i);
        bf16 tmp[4] = {f2b(v.x), f2b(v.y), f2b(v.z), f2b(v.w)};
        *reinterpret_cast<ushort4*>(cd.dst + i) = *reinterpret_cast<const ushort4*>(tmp);
    }
}

// ---------------------------------------------------------------------------
// Gather bf16 embedding rows (512 bf16 = 256 u32 per row), one block per row.
__global__ __launch_bounds__(256) void k_gather(const unsigned int* __restrict__ table,
                                                const int* __restrict__ idx,
                                                unsigned int* __restrict__ out) {
    int r = blockIdx.x;
    out[(size_t)r * 256 + threadIdx.x] = table[(size_t)idx[r] * 256 + threadIdx.x];
}

// ---------------------------------------------------------------------------
// Generic big tiled GEMM: C = A(MxK) @ Bw(NxK)^T  (both row-major, bf16)
// mode 0: outF fp32 = C + bias ; mode 1: tanh ; mode 2: logits remap ; mode 3: bf16+bias
// xcdmap=1: group M-tiles of one N-strip consecutively on one XCD (L2 reuse).
__global__ __launch_bounds__(256) void k_gemm_bt(const bf16* __restrict__ A,
                                                 const bf16* __restrict__ Bw,
                                                 const float* __restrict__ bias,
                                                 float* __restrict__ outF,
                                                 bf16* __restrict__ outB,
                                                 int M, int N, int K, int ldo,
                                                 int ntN, int mode, int xcdmap) {
    int bx = blockIdx.x;
    int mt, nt;
    if (xcdmap) {
        int ntM = (M + 127) >> 7;
        int x = bx & 7, w = bx >> 3;
        mt = w % ntM;
        nt = (w / ntM) * 8 + x;
        if (nt >= ntN) return;
    } else {
        mt = bx / ntN;
        nt = bx % ntN;
    }
    int tid = threadIdx.x, wv = tid >> 6, l = tid & 63;
    int m0 = mt * 128 + (wv >> 1) * 64;
    int n0 = nt * 128 + (wv & 1) * 64;
    int r = l & 15, ko = (l >> 4) * 8;

    const bf16* ap[4];
    const bf16* bp[4];
#pragma unroll
    for (int i = 0; i < 4; ++i) {
        int row = m0 + i * 16 + r;
        if (row > M - 1) row = M - 1;
        ap[i] = A + (size_t)row * K + ko;
    }
#pragma unroll
    for (int j = 0; j < 4; ++j) {
        int n = n0 + j * 16 + r;
        if (n > N - 1) n = N - 1;
        bp[j] = Bw + (size_t)n * K + ko;
    }

    f32x4 zv = {0.f, 0.f, 0.f, 0.f};
    f32x4 acc[4][4];
#pragma unroll
    for (int i = 0; i < 4; ++i)
#pragma unroll
        for (int j = 0; j < 4; ++j) acc[i][j] = zv;

    int nk = K >> 5;
    for (int kk = 0; kk < nk; ++kk) {
        bf16x8 af[4], bfv[4];
#pragma unroll
        for (int i = 0; i < 4; ++i) af[i] = ld8(ap[i] + kk * 32);
#pragma unroll
        for (int j = 0; j < 4; ++j) bfv[j] = ld8(bp[j] + kk * 32);
#pragma unroll
        for (int i = 0; i < 4; ++i)
#pragma unroll
            for (int j = 0; j < 4; ++j) acc[i][j] = MFMA(af[i], bfv[j], acc[i][j]);
    }

    int ccol = l & 15, cr = (l >> 4) * 4;
#pragma unroll
    for (int i = 0; i < 4; ++i) {
#pragma unroll
        for (int j = 0; j < 4; ++j) {
            int n = n0 + j * 16 + ccol;
            if (n >= N) continue;
            float bv = bias ? bias[n] : 0.f;
#pragma unroll
            for (int q = 0; q < 4; ++q) {
                int row = m0 + i * 16 + cr + q;
                if (row >= M) continue;
                float v = acc[i][j][q] + bv;
                if (mode == 1) v = tanhf(v);
                if (mode == 2) {
                    outF[((size_t)(row & 31) * 19 + (size_t)(row >> 5)) * 32000 + n] = v;
                } else if (mode == 3) {
                    outB[(size_t)row * ldo + n] = f2b(v);
                } else {
                    outF[(size_t)row * ldo + n] = v;
                }
            }
        }
    }
}

// ---------------------------------------------------------------------------
// Small-M GEMM: one 16x16 tile per block (64 threads = 1 wave).
// act: 0 none, 1 relu, 2 tanh.
__global__ __launch_bounds__(64) void k_gemm_sm(const bf16* __restrict__ A,
                                                const bf16* __restrict__ W,
                                                const float* __restrict__ bias,
                                                float* __restrict__ outF, int ldof,
                                                bf16* __restrict__ outB, int ldob,
                                                int K, int ntN, int act) {
    int bx = blockIdx.x;
    int mt = bx / ntN, nt = bx % ntN;
    int l = threadIdx.x;
    int r = l & 15, ko = (l >> 4) * 8;
    const bf16* ap = A + (size_t)(mt * 16 + r) * K + ko;
    const bf16* bp = W + (size_t)(nt * 16 + r) * K + ko;
    f32x4 acc = {0.f, 0.f, 0.f, 0.f};
    int nk = K >> 5;
#pragma unroll 4
    for (int kk = 0; kk < nk; ++kk) acc = MFMA(ld8(ap + kk * 32), ld8(bp + kk * 32), acc);
    int n = nt * 16 + (l & 15);
    int cr = (l >> 4) * 4;
    float bv = bias ? bias[n] : 0.f;
#pragma unroll
    for (int q = 0; q < 4; ++q) {
        int row = mt * 16 + cr + q;
        float v = acc[q] + bv;
        if (act == 1) v = fmaxf(v, 0.f);
        if (act == 2) v = tanhf(v);
        if (outF) outF[(size_t)row * ldof + n] = v;
        if (outB) outB[(size_t)row * ldob + n] = f2b(v);
    }
}

// ---------------------------------------------------------------------------
// Persistent encoder, 128 LSTM steps. ROUND-13 VERSION VERBATIM (passing).
// Grid 256 = 4 batch-groups x 64 j-blocks. Gate-per-wave, j-slice of 16
// (Whh rows in registers), group's 8 batches. DO NOT MODIFY THE EXCHANGE.
__global__ __launch_bounds__(256, 1) void k_enc_all(const bf16* __restrict__ Zx,
                                                    const bf16* __restrict__ Whh,
                                                    const float* __restrict__ bih,
                                                    const float* __restrict__ bhh,
                                                    const int* __restrict__ lens,
                                                    unsigned int* __restrict__ hbw0,
                                                    unsigned int* __restrict__ hbw1,
                                                    bf16* __restrict__ cbT,
                                                    bf16* __restrict__ SH,
                                                    int* __restrict__ flags) {
    __shared__ bf16 hlds[8][1024];           // 16KB staged group h, swizzled 16B units
    __shared__ float zl[4][8][16];           // 2KB gate outputs
    __shared__ unsigned short hpub[8][16];   // publish staging
    unsigned int* hldsw = (unsigned int*)hlds;
    const bf16x8* hldsv = (const bf16x8*)hlds;

    int bid = blockIdx.x;
    int grp = bid >> 6, jblk = bid & 63;
    int j0 = jblk * 16;
    int tid = threadIdx.x;
    int g = tid >> 6, l = tid & 63;
    int r = l & 15, ko = (l >> 4) * 8;

    // Whh slice -> registers (16 rows x 1024 K per wave), loaded once.
    bf16x8 wreg[32];
    {
        const bf16* wp = Whh + (size_t)(g * 1024 + j0 + r) * 1024 + ko;
#pragma unroll
        for (int kk = 0; kk < 32; ++kk) wreg[kk] = ld8(wp + kk * 32);
    }

    // Pointwise ownership (tid < 128): one (batch, j) element.
    int bl = tid >> 4, ji = tid & 15;   // bl in [0,8) for tid<128
    int b = grp * 8 + bl;
    int j = j0 + ji;
    bool pw = tid < 128;
    float bs[4] = {0.f, 0.f, 0.f, 0.f};
    int lenv = 0;
    float hs = 0.f, cs = 0.f;
    const bf16* zxp = Zx;
    if (pw) {
#pragma unroll
        for (int gg = 0; gg < 4; ++gg) bs[gg] = bih[gg * 1024 + j] + bhh[gg * 1024 + j];
        lenv = lens[b];
        zxp = Zx + (size_t)(b * 128) * 4096 + j;
    }
    int ccol = l & 15, cr = (l >> 4) * 4;
    int rk = r & 7;                       // XOR swizzle key (row & 7)
    unsigned int gbase = grp * 4096;      // group's u32 offset into h buffers

    for (int t = 0; t < 128; ++t) {
        // Prefetch Zx[t] (independent of barrier) — hides latency under spin.
        float za[4] = {0.f, 0.f, 0.f, 0.f};
        if (pw) {
#pragma unroll
            for (int gg = 0; gg < 4; ++gg)
                za[gg] = b2f(zxp[(size_t)t * 4096 + gg * 1024]);
        }

        // Wait for this group's 64 producers of h_t (t=0: initial zeros).
        if (t > 0) {
            if (tid < 64) {
                const int* fp = flags + (t - 1) * 256 + grp * 64;
                while (true) {
                    int v = __hip_atomic_load(fp + l, __ATOMIC_RELAXED,
                                              __HIP_MEMORY_SCOPE_AGENT);
                    if (__all(v != 0)) break;
                    __builtin_amdgcn_s_sleep(1);
                }
                __builtin_amdgcn_sched_barrier(0);  // pin compile-time order
            }
            __syncthreads();
        }

        // Stage group h_t (4096 u32) LLC -> LDS, swizzled: unit u -> u^(row&7).
        // PROVEN interleaved form (unroll 4, one load one write) — DO NOT
        // reschedule (rounds 5/6/7/12/14 all corrupted deterministically).
        const unsigned int* hw = ((t & 1) ? hbw1 : hbw0) + gbase;
#pragma unroll 4
        for (int i = 0; i < 16; ++i) {
            int d = i * 256 + tid;
            int bb = d >> 9, w = d & 511;
            unsigned int v = __hip_atomic_load(hw + d, __ATOMIC_RELAXED,
                                               __HIP_MEMORY_SCOPE_AGENT);
            hldsw[bb * 512 + ((((w >> 2) ^ (bb & 7)) << 2) | (w & 3))] = v;
        }
        __syncthreads();

        // z[g] slice = h @ Whh[g-slice]^T from LDS. Only 8 valid M rows;
        // lanes with (l&15)>=8 read aliased rows (results discarded — matmul
        // rows are independent).
        f32x4 acc0 = {0.f, 0.f, 0.f, 0.f};
#pragma unroll
        for (int kk = 0; kk < 32; ++kk) {
            int u = kk * 4 + (l >> 4);
            acc0 = MFMA(hldsv[(r & 7) * 128 + (u ^ rk)], wreg[kk], acc0);
        }
        if (l < 32) {
#pragma unroll
            for (int q = 0; q < 4; ++q) zl[g][cr + q][ccol] = acc0[q];
        }
        __syncthreads();

        // Fused pointwise: one (b, j) element per thread (tid < 128).
        if (pw) {
            float zi = zl[0][bl][ji] + za[0] + bs[0];
            float zf = zl[1][bl][ji] + za[1] + bs[1];
            float zg = zl[2][bl][ji] + za[2] + bs[2];
            float zo = zl[3][bl][ji] + za[3] + bs[3];
            float cn = sigf(zf) * cs + sigf(zi) * tanhf(zg);
            float hn = sigf(zo) * tanhf(cn);
            bool msk = t < lenv;
            if (msk) { hs = hn; cs = cn; }
            hpub[bl][ji] = b2u(f2b(hs));
            SH[((size_t)b * 128 + t) * 1024 + j] = msk ? f2b(hn) : f2b(0.f);
            if (t == 127) cbT[b * 1024 + j] = f2b(cs);
        }
        __syncthreads();

        // Publish this block's h_{t+1} slice (8 b x 16 j = 64 u32) to LLC.
        unsigned int* hwn = ((t & 1) ? hbw0 : hbw1) + gbase;
        if (tid < 64) {
            int pb = tid >> 3, pq = tid & 7;
            unsigned int val = (unsigned int)hpub[pb][2 * pq] |
                               ((unsigned int)hpub[pb][2 * pq + 1] << 16);
            __hip_atomic_store(hwn + (size_t)pb * 512 + (j0 >> 1) + pq, val,
                               __ATOMIC_RELAXED, __HIP_MEMORY_SCOPE_AGENT);
        }
        __syncthreads();  // vmcnt(0) drain: publish stores acked at LLC
        if (tid == 0)
            __hip_atomic_fetch_add(flags + t * 256 + grp * 64 + jblk, 1,
                                   __ATOMIC_RELAXED, __HIP_MEMORY_SCOPE_AGENT);
    }
}

// ---------------------------------------------------------------------------
// Decoder attention step with fused a_key. Grid 128 = 32 b x 4 j-chunks.
// a_key = tanh(h @ ak_W^T + ak_b) per block (bf16 scalar dot, akW L2-resident);
// then energy/softmax/context. ctx -> xin and featT (cols 1024+).
__global__ __launch_bounds__(256) void k_attn(const bf16* __restrict__ embedB,
                                              const int* __restrict__ trg,
                                              const bf16* __restrict__ akWB,
                                              const float* __restrict__ akb,
                                              const float* __restrict__ qkB,
                                              const bf16* __restrict__ qvBb,
                                              const int* __restrict__ lens,
                                              const bf16* __restrict__ hb,
                                              bf16* __restrict__ xin,
                                              bf16* __restrict__ featT, int t) {
    int b = blockIdx.x >> 2, chunk = blockIdx.x & 3;
    int tid = threadIdx.x;
    if (chunk == 0) {
        const unsigned int* er = (const unsigned int*)(embedB + (size_t)trg[b * 20 + t] * 512);
        ((unsigned int*)(xin + (size_t)b * 1536))[tid] = er[tid];
    }

    __shared__ float part[256];
    __shared__ float ak[100];
    __shared__ float ew[128];
    __shared__ float mxs, inv_s;

    // a_key: 2 threads per output (K halves of 512), bf16 inputs.
    float s = 0.f;
    if (tid < 200) {
        int n = tid >> 1, hh = tid & 1;
        const bf16* wr = akWB + (size_t)n * 1024 + hh * 512;
        const bf16* hr = hb + (size_t)b * 1024 + hh * 512;
#pragma unroll 8
        for (int k = 0; k < 512; ++k) s += b2f(hr[k]) * b2f(wr[k]);
    }
    part[tid] = s;
    __syncthreads();
    if (tid < 100) ak[tid] = tanhf(part[2 * tid] + part[2 * tid + 1] + akb[tid]);
    __syncthreads();

    if (tid < 128) {
        const float* qr = qkB + ((size_t)b * 128 + tid) * 100;
        float e = 0.f;
#pragma unroll 4
        for (int k = 0; k < 100; ++k) e += qr[k] * ak[k];
        ew[tid] = (tid < lens[b]) ? e : -INFINITY;
    }
    __syncthreads();
    if (tid < 64) {
        float m = fmaxf(ew[tid], ew[tid + 64]);
#pragma unroll
        for (int off = 32; off; off >>= 1) m = fmaxf(m, __shfl_down(m, off));
        if (tid == 0) mxs = m;
    }
    __syncthreads();
    if (tid < 128) ew[tid] = expf(ew[tid] - mxs);  // masked -> 0
    __syncthreads();
    if (tid < 64) {
        float s2 = ew[tid] + ew[tid + 64];
#pragma unroll
        for (int off = 32; off; off >>= 1) s2 += __shfl_down(s2, off);
        if (tid == 0) inv_s = 1.0f / s2;
    }
    __syncthreads();

    {
        int jj = (chunk << 8) + tid;
        const bf16* qvb = qvBb + ((size_t)b * 128) * 1024 + jj;
        float a0 = 0.f;
#pragma unroll 4
        for (int s3 = 0; s3 < 128; ++s3) a0 += ew[s3] * b2f(qvb[(size_t)s3 * 1024]);
        a0 *= inv_s;
        bf16 cb = f2b(a0);
        xin[(size_t)b * 1536 + 512 + jj] = cb;
        featT[(size_t)b * 2048 + 1024 + jj] = cb;
    }
}

// ---------------------------------------------------------------------------
// Decoder LSTM step. Grid 256 blocks x 64 thr; gates x 4 j packed in N-tile.
// h state bf16 (hb_in/hb_out); c state fp32 (cd). hn also -> featT cols 0-1023.
__global__ __launch_bounds__(64) void k_dec_z(const bf16* __restrict__ xin,
                                              const bf16* __restrict__ Wih,
                                              const bf16* __restrict__ hb_in,
                                              const bf16* __restrict__ Whh,
                                              const float* __restrict__ bih,
                                              const float* __restrict__ bhh,
                                              float* __restrict__ cd,
                                              bf16* __restrict__ hb_out,
                                              bf16* __restrict__ featT) {
    __shared__ float zl[32][16];
    int j0 = blockIdx.x * 4;
    int l = threadIdx.x;
    int r = l & 15, ko = (l >> 4) * 8;
    int wrow = (r >> 2) * 1024 + j0 + (r & 3);

    f32x4 acc0 = {0.f, 0.f, 0.f, 0.f}, acc1 = {0.f, 0.f, 0.f, 0.f};
    {
        const bf16* a0 = xin + (size_t)r * 1536 + ko;
        const bf16* a1 = xin + (size_t)(16 + r) * 1536 + ko;
        const bf16* bp = Wih + (size_t)wrow * 1536 + ko;
#pragma unroll 4
        for (int kk = 0; kk < 48; ++kk) {
            bf16x8 bv = ld8(bp + kk * 32);
            acc0 = MFMA(ld8(a0 + kk * 32), bv, acc0);
            acc1 = MFMA(ld8(a1 + kk * 32), bv, acc1);
        }
    }
    {
        const bf16* a0 = hb_in + (size_t)r * 1024 + ko;
        const bf16* a1 = hb_in + (size_t)(16 + r) * 1024 + ko;
        const bf16* bp = Whh + (size_t)wrow * 1024 + ko;
#pragma unroll 4
        for (int kk = 0; kk < 32; ++kk) {
            bf16x8 bv = ld8(bp + kk * 32);
            acc0 = MFMA(ld8(a0 + kk * 32), bv, acc0);
            acc1 = MFMA(ld8(a1 + kk * 32), bv, acc1);
        }
    }
    int ccol = l & 15, cr = (l >> 4) * 4;
#pragma unroll
    for (int q = 0; q < 4; ++q) {
        zl[cr + q][ccol] = acc0[q];
        zl[16 + cr + q][ccol] = acc1[q];
    }
    __syncthreads();

#pragma unroll
    for (int e = l; e < 128; e += 64) {
        int b = e >> 2, jj = e & 3;
        int j = j0 + jj;
        float zi = zl[b][jj]      + bih[j]        + bhh[j];
        float zf = zl[b][4 + jj]  + bih[1024 + j] + bhh[1024 + j];
        float zg = zl[b][8 + jj]  + bih[2048 + j] + bhh[2048 + j];
        float zo = zl[b][12 + jj] + bih[3072 + j] + bhh[3072 + j];
        int hi = b * 1024 + j;
        float co = cd[hi];
        float cn = sigf(zf) * co + sigf(zi) * tanhf(zg);
        float hn = sigf(zo) * tanhf(cn);
        cd[hi] = cn;
        bf16 hnb = f2b(hn);
        hb_out[hi] = hnb;
        featT[(size_t)b * 2048 + j] = hnb;
    }
}

// ---------------------------------------------------------------------------
extern "C" void kernel_launch(void* const* d_in, const int* in_sizes, int n_in,
                              void* d_out, int out_size, void* d_ws, size_t ws_size,
                              hipStream_t stream) {
    const float* embed   = (const float*)d_in[0];
    const float* enc_Wih = (const float*)d_in[1];
    const float* enc_Whh = (const float*)d_in[2];
    const float* enc_bih = (const float*)d_in[3];
    const float* enc_bhh = (const float*)d_in[4];
    const float* dec_Wih = (const float*)d_in[5];
    const float* dec_Whh = (const float*)d_in[6];
    const float* dec_bih = (const float*)d_in[7];
    const float* dec_bhh = (const float*)d_in[8];
    const float* qk_W    = (const float*)d_in[9];
    const float* qk_b    = (const float*)d_in[10];
    const float* qv_W    = (const float*)d_in[11];
    const float* qv_b    = (const float*)d_in[12];
    const float* ak_W    = (const float*)d_in[13];
    const float* ak_b    = (const float*)d_in[14];
    const float* out_W   = (const float*)d_in[15];
    const float* out_b   = (const float*)d_in[16];
    const float* wd_b    = (const float*)d_in[17];
    const float* hfc1_W  = (const float*)d_in[18];
    const float* hfc1_b  = (const float*)d_in[19];
    const float* hfc2_W  = (const float*)d_in[20];
    const float* hfc2_b  = (const float*)d_in[21];
    const float* cfc1_W  = (const float*)d_in[22];
    const float* cfc1_b  = (const float*)d_in[23];
    const float* cfc2_W  = (const float*)d_in[24];
    const float* cfc2_b  = (const float*)d_in[25];
    const int* src  = (const int*)d_in[26];
    const int* lens = (const int*)d_in[27];
    const int* trg  = (const int*)d_in[28];

    char* cur = (char*)d_ws;
    auto alloc = [&](size_t bytes) -> char* {
        char* p = cur;
        cur += (bytes + 255) & ~(size_t)255;
        return p;
    };
    bf16* embedB  = (bf16*)alloc((size_t)16384000 * 2);
    bf16* encWihB = (bf16*)alloc((size_t)2097152 * 2);
    bf16* encWhhB = (bf16*)alloc((size_t)4194304 * 2);
    bf16* decWihB = (bf16*)alloc((size_t)6291456 * 2);
    bf16* decWhhB = (bf16*)alloc((size_t)4194304 * 2);
    bf16* qkWB    = (bf16*)alloc((size_t)102400 * 2);
    bf16* qvWB    = (bf16*)alloc((size_t)1048576 * 2);
    bf16* outWB   = (bf16*)alloc((size_t)1048576 * 2);
    bf16* hfc1B   = (bf16*)alloc((size_t)2097152 * 2);
    bf16* hfc2B   = (bf16*)alloc((size_t)2097152 * 2);
    bf16* cfc1B   = (bf16*)alloc((size_t)2097152 * 2);
    bf16* cfc2B   = (bf16*)alloc((size_t)2097152 * 2);
    bf16* akWB    = (bf16*)alloc((size_t)102400 * 2);
    bf16*  Xsrc  = (bf16*)alloc((size_t)4096 * 512 * 2);
    bf16*  Zx    = (bf16*)alloc((size_t)4096 * 4096 * 2);
    bf16*  SH    = (bf16*)alloc((size_t)4096 * 1024 * 2);
    float* qkB   = (float*)alloc((size_t)4096 * 100 * 4);
    bf16*  qvBb  = (bf16*)alloc((size_t)4096 * 1024 * 2);   // q_value in bf16
    bf16*  hbA   = (bf16*)alloc(32 * 1024 * 2);
    bf16*  hbB   = (bf16*)alloc(32 * 1024 * 2);
    bf16*  cbT   = (bf16*)alloc(32 * 1024 * 2);
    bf16*  t1    = (bf16*)alloc(32 * 2048 * 2);
    float* cd    = (float*)alloc(32 * 1024 * 4);
    bf16*  hdA   = (bf16*)alloc(32 * 1024 * 2);
    bf16*  hdB   = (bf16*)alloc(32 * 1024 * 2);
    bf16*  xin   = (bf16*)alloc(32 * 1536 * 2);
    bf16*  featAll = (bf16*)alloc((size_t)608 * 2048 * 2);  // [t*32+b][h | ctx]
    bf16*  feats = (bf16*)alloc((size_t)608 * 512 * 2);
    int*   flags = (int*)alloc((size_t)128 * 256 * 4);
    if ((size_t)(cur - (char*)d_ws) > ws_size) return;  // workspace too small

    hipMemsetAsync(hbA, 0, 32 * 1024 * 2, stream);
    hipMemsetAsync(flags, 0, (size_t)128 * 256 * 4, stream);

    ConvTable tab;
    tab.d[0]  = {embed,   embedB,  16384000};
    tab.d[1]  = {enc_Wih, encWihB, 2097152};
    tab.d[2]  = {enc_Whh, encWhhB, 4194304};
    tab.d[3]  = {dec_Wih, decWihB, 6291456};
    tab.d[4]  = {dec_Whh, decWhhB, 4194304};
    tab.d[5]  = {qk_W,    qkWB,    102400};
    tab.d[6]  = {qv_W,    qvWB,    1048576};
    tab.d[7]  = {out_W,   outWB,   1048576};
    tab.d[8]  = {hfc1_W,  hfc1B,   2097152};
    tab.d[9]  = {hfc2_W,  hfc2B,   2097152};
    tab.d[10] = {cfc1_W,  cfc1B,   2097152};
    tab.d[11] = {cfc2_W,  cfc2B,   2097152};
    tab.d[12] = {ak_W,    akWB,    102400};
    k_conv<<<dim3(1024, 13), 256, 0, stream>>>(tab);

    k_gather<<<4096, 256, 0, stream>>>((const unsigned int*)embedB, src, (unsigned int*)Xsrc);

    // Zx = Xsrc @ enc_Wih^T  (M=4096, N=4096, K=512), bf16 out
    k_gemm_bt<<<32 * 32, 256, 0, stream>>>(Xsrc, encWihB, nullptr, nullptr, Zx,
                                           4096, 4096, 512, 4096, 32, 3, 0);

    // Persistent encoder (cooperative launch for co-residency only).
    {
        const bf16* ZxA = Zx;  const bf16* WhhA = encWhhB;
        const float* bihA = enc_bih; const float* bhhA = enc_bhh;
        const int* lensA = lens;
        unsigned int* hb0A = (unsigned int*)hbA;
        unsigned int* hb1A = (unsigned int*)hbB;
        bf16* cbTA = cbT; bf16* SHA = SH; int* flagsA = flags;
        void* args[] = {(void*)&ZxA, (void*)&WhhA, (void*)&bihA, (void*)&bhhA,
                        (void*)&lensA, (void*)&hb0A, (void*)&hb1A, (void*)&cbTA,
                        (void*)&SHA, (void*)&flagsA};
        hipLaunchCooperativeKernel((void*)k_enc_all, dim3(256), dim3(256), args, 0, stream);
    }
    bf16* hbT = hbA;  // publish target at t=127 (odd) is hbw0 == hbA

    k_gemm_sm<<<256, 64, 0, stream>>>(hbT, hfc1B, hfc1_b, nullptr, 0, t1, 2048, 1024, 128, 1);
    k_gemm_sm<<<128, 64, 0, stream>>>(t1, hfc2B, hfc2_b, nullptr, 0, hdA, 1024, 2048, 64, 0);
    k_gemm_sm<<<256, 64, 0, stream>>>(cbT, cfc1B, cfc1_b, nullptr, 0, t1, 2048, 1024, 128, 1);
    k_gemm_sm<<<128, 64, 0, stream>>>(t1, cfc2B, cfc2_b, cd, 1024, nullptr, 0, 2048, 64, 0);

    k_gemm_bt<<<32, 256, 0, stream>>>(SH, qkWB, qk_b, qkB, nullptr,
                                      4096, 100, 1024, 100, 1, 1, 0);
    k_gemm_bt<<<256, 256, 0, stream>>>(SH, qvWB, qv_b, nullptr, qvBb,
                                       4096, 1024, 1024, 1024, 8, 3, 0);

    // Decoder: 2 kernels per step (a_key fused into attn; out-GEMM deferred).
    for (int t = 0; t < 19; ++t) {
        const bf16* hin = (t & 1) ? hdB : hdA;
        bf16* hout = (t & 1) ? hdA : hdB;
        bf16* featT = featAll + (size_t)t * 32 * 2048;
        k_attn<<<128, 256, 0, stream>>>(embedB, trg, akWB, ak_b, qkB, qvBb, lens,
                                        hin, xin, featT, t);
        k_dec_z<<<256, 64, 0, stream>>>(xin, decWihB, hin, decWhhB, dec_bih, dec_bhh,
                                        cd, hout, featT);
    }

    // Batched out-projection: feats(608x512) = featAll(608x2048) @ out_W^T.
    k_gemm_bt<<<20, 256, 0, stream>>>(featAll, outWB, out_b, nullptr, feats,
                                      608, 512, 2048, 512, 4, 3, 0);

    // Logits: feats(608x512) @ embed^T(32000x512) + wd_b, XCD-grouped mapping.
    k_gemm_bt<<<1280, 256, 0, stream>>>(feats, embedB, wd_b, (float*)d_out, nullptr,
                                        608, 32000, 512, 0, 250, 2, 1);
}

// Round 16
// 2051.464 us; speedup vs baseline: 2.1180x; 1.0519x over previous
//
#include <hip/hip_runtime.h>
#include <hip/hip_bf16.h>

// Problem constants: B=32, S=128, T=20 (19 dec steps), H=1024, D=512, K_attn=100, V=32000
// Inputs float32; output d_out float32 (B,19,V).
// Encoder: round-13/15 kernel VERBATIM (passing, 713us). Exchange FROZEN
// (5 failed variants: rounds 5/6/7/12/14).
// Round 16: k_gemm_bt rewritten with global_load_lds staging (m97 ladder
// recipe): 128x128 tile, BK=32, width-16 DMA into linear LDS with
// pre-swizzled GLOBAL source (unit (row,uc) <- global (row, uc^(row&3))),
// ds_read_b128 fragments with matching XOR. Epilogue/modes unchanged.

using bf16 = __hip_bfloat16;
typedef __attribute__((ext_vector_type(8))) __bf16 bf16x8;
typedef __attribute__((ext_vector_type(4))) float f32x4;

__device__ __forceinline__ bf16x8 ld8(const bf16* p) {
    return *reinterpret_cast<const bf16x8*>(p);
}
__device__ __forceinline__ float b2f(bf16 v) { return __bfloat162float(v); }
__device__ __forceinline__ bf16 f2b(float v) { return __float2bfloat16(v); }
__device__ __forceinline__ unsigned short b2u(bf16 v) {
    unsigned short u; __builtin_memcpy(&u, &v, 2); return u;
}
__device__ __forceinline__ float sigf(float x) { return 1.0f / (1.0f + expf(-x)); }

#define MFMA(a, b, c) __builtin_amdgcn_mfma_f32_16x16x32_bf16((a), (b), (c), 0, 0, 0)

__device__ __forceinline__ void gload_lds16(const bf16* g, bf16* l) {
    __builtin_amdgcn_global_load_lds(
        (const __attribute__((address_space(1))) void*)g,
        (__attribute__((address_space(3))) void*)l, 16, 0, 0);
}

// ---------------------------------------------------------------------------
// f32 -> bf16 conversion for weight tensors. blockIdx.y selects tensor.
struct ConvDesc { const float* src; bf16* dst; int n; };
struct ConvTable { ConvDesc d[13]; };

__global__ __launch_bounds__(256) void k_conv(ConvTable tab) {
    ConvDesc cd = tab.d[blockIdx.y];
    int stride = gridDim.x * blockDim.x * 4;
    for (int i = (blockIdx.x * blockDim.x + threadIdx.x) * 4; i < cd.n; i += stride) {
        float4 v = *reinterpret_cast<const float4*>(cd.src + i);
        bf16 tmp[4] = {f2b(v.x), f2b(v.y), f2b(v.z), f2b(v.w)};
        *reinterpret_cast<ushort4*>(cd.dst + i) = *reinterpret_cast<const ushort4*>(tmp);
    }
}

// ---------------------------------------------------------------------------
// Gather bf16 embedding rows (512 bf16 = 256 u32 per row), one block per row.
__global__ __launch_bounds__(256) void k_gather(const unsigned int* __restrict__ table,
                                                const int* __restrict__ idx,
                                                unsigned int* __restrict__ out) {
    int r = blockIdx.x;
    out[(size_t)r * 256 + threadIdx.x] = table[(size_t)idx[r] * 256 + threadIdx.x];
}

// ---------------------------------------------------------------------------
// LDS-staged tiled GEMM: C = A(MxK) @ Bw(NxK)^T (both row-major, bf16).
// 128x128 tile, BK=32, global_load_lds width-16 staging, pre-swizzled global
// source so LDS stays linear; ds_read with matching XOR (bank spread).
// mode 0: outF fp32 = C + bias ; mode 1: tanh ; mode 2: logits remap ; mode 3: bf16+bias
// xcdmap=1: group M-tiles of one N-strip consecutively on one XCD (L2 reuse).
__global__ __launch_bounds__(256) void k_gemm_bt(const bf16* __restrict__ A,
                                                 const bf16* __restrict__ Bw,
                                                 const float* __restrict__ bias,
                                                 float* __restrict__ outF,
                                                 bf16* __restrict__ outB,
                                                 int M, int N, int K, int ldo,
                                                 int ntN, int mode, int xcdmap) {
    __shared__ __attribute__((aligned(16))) bf16 ldsA[128 * 32];
    __shared__ __attribute__((aligned(16))) bf16 ldsB[128 * 32];

    int bx = blockIdx.x;
    int mt, nt;
    if (xcdmap) {
        int ntM = (M + 127) >> 7;
        int x = bx & 7, w = bx >> 3;
        mt = w % ntM;
        nt = (w / ntM) * 8 + x;
        if (nt >= ntN) return;
    } else {
        mt = bx / ntN;
        nt = bx % ntN;
    }
    int tid = threadIdx.x, wv = tid >> 6, l = tid & 63;
    int m0 = mt * 128, n0 = nt * 128;
    int m0w = (wv >> 1) * 64;      // wave tile offset within block tile
    int n0w = (wv & 1) * 64;
    int r = l & 15, ko = l >> 4;   // ko = 16B k-unit 0..3

    // Staging geometry: wave wv, call c covers rows rbase..rbase+15 (16 rows x
    // 4 units = 64 lanes x 16B). Lane l: row = rbase + (l>>2), uc = l&3;
    // global col-unit = uc ^ (row&3)  (inverse of the read-side XOR).
    int srow0 = (l >> 2), suc = l & 3;

    f32x4 zv = {0.f, 0.f, 0.f, 0.f};
    f32x4 acc[4][4];
#pragma unroll
    for (int i = 0; i < 4; ++i)
#pragma unroll
        for (int j = 0; j < 4; ++j) acc[i][j] = zv;

    const bf16x8* LA = (const bf16x8*)ldsA;
    const bf16x8* LB = (const bf16x8*)ldsB;

    for (int kk = 0; kk < K; kk += 32) {
        __syncthreads();  // previous iteration's LDS reads complete
#pragma unroll
        for (int c = 0; c < 2; ++c) {
            int rbase = c * 64 + wv * 16;
            int row = rbase + srow0;
            int gcu = (suc ^ (row & 3)) << 3;  // swizzled col offset in elems
            int arow = m0 + row; if (arow > M - 1) arow = M - 1;
            int brow = n0 + row; if (brow > N - 1) brow = N - 1;
            gload_lds16(A + (size_t)arow * K + kk + gcu, ldsA + rbase * 32);
            gload_lds16(Bw + (size_t)brow * K + kk + gcu, ldsB + rbase * 32);
        }
        __syncthreads();  // staging drained (vmcnt(0) before barrier)

        bf16x8 af[4], bfv[4];
#pragma unroll
        for (int i = 0; i < 4; ++i) {
            int row = m0w + i * 16 + r;
            af[i] = LA[row * 4 + (ko ^ (row & 3))];
        }
#pragma unroll
        for (int j = 0; j < 4; ++j) {
            int row = n0w + j * 16 + r;
            bfv[j] = LB[row * 4 + (ko ^ (row & 3))];
        }
#pragma unroll
        for (int i = 0; i < 4; ++i)
#pragma unroll
            for (int j = 0; j < 4; ++j) acc[i][j] = MFMA(af[i], bfv[j], acc[i][j]);
    }

    int ccol = l & 15, cr = (l >> 4) * 4;
#pragma unroll
    for (int i = 0; i < 4; ++i) {
#pragma unroll
        for (int j = 0; j < 4; ++j) {
            int n = n0 + n0w + j * 16 + ccol;
            if (n >= N) continue;
            float bv = bias ? bias[n] : 0.f;
#pragma unroll
            for (int q = 0; q < 4; ++q) {
                int row = m0 + m0w + i * 16 + cr + q;
                if (row >= M) continue;
                float v = acc[i][j][q] + bv;
                if (mode == 1) v = tanhf(v);
                if (mode == 2) {
                    outF[((size_t)(row & 31) * 19 + (size_t)(row >> 5)) * 32000 + n] = v;
                } else if (mode == 3) {
                    outB[(size_t)row * ldo + n] = f2b(v);
                } else {
                    outF[(size_t)row * ldo + n] = v;
                }
            }
        }
    }
}

// ---------------------------------------------------------------------------
// Small-M GEMM: one 16x16 tile per block (64 threads = 1 wave).
// act: 0 none, 1 relu, 2 tanh.
__global__ __launch_bounds__(64) void k_gemm_sm(const bf16* __restrict__ A,
                                                const bf16* __restrict__ W,
                                                const float* __restrict__ bias,
                                                float* __restrict__ outF, int ldof,
                                                bf16* __restrict__ outB, int ldob,
                                                int K, int ntN, int act) {
    int bx = blockIdx.x;
    int mt = bx / ntN, nt = bx % ntN;
    int l = threadIdx.x;
    int r = l & 15, ko = (l >> 4) * 8;
    const bf16* ap = A + (size_t)(mt * 16 + r) * K + ko;
    const bf16* bp = W + (size_t)(nt * 16 + r) * K + ko;
    f32x4 acc = {0.f, 0.f, 0.f, 0.f};
    int nk = K >> 5;
#pragma unroll 4
    for (int kk = 0; kk < nk; ++kk) acc = MFMA(ld8(ap + kk * 32), ld8(bp + kk * 32), acc);
    int n = nt * 16 + (l & 15);
    int cr = (l >> 4) * 4;
    float bv = bias ? bias[n] : 0.f;
#pragma unroll
    for (int q = 0; q < 4; ++q) {
        int row = mt * 16 + cr + q;
        float v = acc[q] + bv;
        if (act == 1) v = fmaxf(v, 0.f);
        if (act == 2) v = tanhf(v);
        if (outF) outF[(size_t)row * ldof + n] = v;
        if (outB) outB[(size_t)row * ldob + n] = f2b(v);
    }
}

// ---------------------------------------------------------------------------
// Persistent encoder, 128 LSTM steps. ROUND-13 VERSION VERBATIM (passing).
// Grid 256 = 4 batch-groups x 64 j-blocks. DO NOT MODIFY THE EXCHANGE.
__global__ __launch_bounds__(256, 1) void k_enc_all(const bf16* __restrict__ Zx,
                                                    const bf16* __restrict__ Whh,
                                                    const float* __restrict__ bih,
                                                    const float* __restrict__ bhh,
                                                    const int* __restrict__ lens,
                                                    unsigned int* __restrict__ hbw0,
                                                    unsigned int* __restrict__ hbw1,
                                                    bf16* __restrict__ cbT,
                                                    bf16* __restrict__ SH,
                                                    int* __restrict__ flags) {
    __shared__ bf16 hlds[8][1024];           // 16KB staged group h, swizzled 16B units
    __shared__ float zl[4][8][16];           // 2KB gate outputs
    __shared__ unsigned short hpub[8][16];   // publish staging
    unsigned int* hldsw = (unsigned int*)hlds;
    const bf16x8* hldsv = (const bf16x8*)hlds;

    int bid = blockIdx.x;
    int grp = bid >> 6, jblk = bid & 63;
    int j0 = jblk * 16;
    int tid = threadIdx.x;
    int g = tid >> 6, l = tid & 63;
    int r = l & 15, ko = (l >> 4) * 8;

    // Whh slice -> registers (16 rows x 1024 K per wave), loaded once.
    bf16x8 wreg[32];
    {
        const bf16* wp = Whh + (size_t)(g * 1024 + j0 + r) * 1024 + ko;
#pragma unroll
        for (int kk = 0; kk < 32; ++kk) wreg[kk] = ld8(wp + kk * 32);
    }

    // Pointwise ownership (tid < 128): one (batch, j) element.
    int bl = tid >> 4, ji = tid & 15;   // bl in [0,8) for tid<128
    int b = grp * 8 + bl;
    int j = j0 + ji;
    bool pw = tid < 128;
    float bs[4] = {0.f, 0.f, 0.f, 0.f};
    int lenv = 0;
    float hs = 0.f, cs = 0.f;
    const bf16* zxp = Zx;
    if (pw) {
#pragma unroll
        for (int gg = 0; gg < 4; ++gg) bs[gg] = bih[gg * 1024 + j] + bhh[gg * 1024 + j];
        lenv = lens[b];
        zxp = Zx + (size_t)(b * 128) * 4096 + j;
    }
    int ccol = l & 15, cr = (l >> 4) * 4;
    int rk = r & 7;                       // XOR swizzle key (row & 7)
    unsigned int gbase = grp * 4096;      // group's u32 offset into h buffers

    for (int t = 0; t < 128; ++t) {
        // Prefetch Zx[t] (independent of barrier) — hides latency under spin.
        float za[4] = {0.f, 0.f, 0.f, 0.f};
        if (pw) {
#pragma unroll
            for (int gg = 0; gg < 4; ++gg)
                za[gg] = b2f(zxp[(size_t)t * 4096 + gg * 1024]);
        }

        // Wait for this group's 64 producers of h_t (t=0: initial zeros).
        if (t > 0) {
            if (tid < 64) {
                const int* fp = flags + (t - 1) * 256 + grp * 64;
                while (true) {
                    int v = __hip_atomic_load(fp + l, __ATOMIC_RELAXED,
                                              __HIP_MEMORY_SCOPE_AGENT);
                    if (__all(v != 0)) break;
                    __builtin_amdgcn_s_sleep(1);
                }
                __builtin_amdgcn_sched_barrier(0);  // pin compile-time order
            }
            __syncthreads();
        }

        // Stage group h_t (4096 u32) LLC -> LDS, swizzled: unit u -> u^(row&7).
        // PROVEN interleaved form (unroll 4, one load one write) — DO NOT
        // reschedule (rounds 5/6/7/12/14 all corrupted deterministically).
        const unsigned int* hw = ((t & 1) ? hbw1 : hbw0) + gbase;
#pragma unroll 4
        for (int i = 0; i < 16; ++i) {
            int d = i * 256 + tid;
            int bb = d >> 9, w = d & 511;
            unsigned int v = __hip_atomic_load(hw + d, __ATOMIC_RELAXED,
                                               __HIP_MEMORY_SCOPE_AGENT);
            hldsw[bb * 512 + ((((w >> 2) ^ (bb & 7)) << 2) | (w & 3))] = v;
        }
        __syncthreads();

        // z[g] slice = h @ Whh[g-slice]^T from LDS. Only 8 valid M rows;
        // lanes with (l&15)>=8 read aliased rows (results discarded — matmul
        // rows are independent).
        f32x4 acc0 = {0.f, 0.f, 0.f, 0.f};
#pragma unroll
        for (int kk = 0; kk < 32; ++kk) {
            int u = kk * 4 + (l >> 4);
            acc0 = MFMA(hldsv[(r & 7) * 128 + (u ^ rk)], wreg[kk], acc0);
        }
        if (l < 32) {
#pragma unroll
            for (int q = 0; q < 4; ++q) zl[g][cr + q][ccol] = acc0[q];
        }
        __syncthreads();

        // Fused pointwise: one (b, j) element per thread (tid < 128).
        if (pw) {
            float zi = zl[0][bl][ji] + za[0] + bs[0];
            float zf = zl[1][bl][ji] + za[1] + bs[1];
            float zg = zl[2][bl][ji] + za[2] + bs[2];
            float zo = zl[3][bl][ji] + za[3] + bs[3];
            float cn = sigf(zf) * cs + sigf(zi) * tanhf(zg);
            float hn = sigf(zo) * tanhf(cn);
            bool msk = t < lenv;
            if (msk) { hs = hn; cs = cn; }
            hpub[bl][ji] = b2u(f2b(hs));
            SH[((size_t)b * 128 + t) * 1024 + j] = msk ? f2b(hn) : f2b(0.f);
            if (t == 127) cbT[b * 1024 + j] = f2b(cs);
        }
        __syncthreads();

        // Publish this block's h_{t+1} slice (8 b x 16 j = 64 u32) to LLC.
        unsigned int* hwn = ((t & 1) ? hbw0 : hbw1) + gbase;
        if (tid < 64) {
            int pb = tid >> 3, pq = tid & 7;
            unsigned int val = (unsigned int)hpub[pb][2 * pq] |
                               ((unsigned int)hpub[pb][2 * pq + 1] << 16);
            __hip_atomic_store(hwn + (size_t)pb * 512 + (j0 >> 1) + pq, val,
                               __ATOMIC_RELAXED, __HIP_MEMORY_SCOPE_AGENT);
        }
        __syncthreads();  // vmcnt(0) drain: publish stores acked at LLC
        if (tid == 0)
            __hip_atomic_fetch_add(flags + t * 256 + grp * 64 + jblk, 1,
                                   __ATOMIC_RELAXED, __HIP_MEMORY_SCOPE_AGENT);
    }
}

// ---------------------------------------------------------------------------
// Decoder attention step with fused a_key. Grid 128 = 32 b x 4 j-chunks.
__global__ __launch_bounds__(256) void k_attn(const bf16* __restrict__ embedB,
                                              const int* __restrict__ trg,
                                              const bf16* __restrict__ akWB,
                                              const float* __restrict__ akb,
                                              const float* __restrict__ qkB,
                                              const bf16* __restrict__ qvBb,
                                              const int* __restrict__ lens,
                                              const bf16* __restrict__ hb,
                                              bf16* __restrict__ xin,
                                              bf16* __restrict__ featT, int t) {
    int b = blockIdx.x >> 2, chunk = blockIdx.x & 3;
    int tid = threadIdx.x;
    if (chunk == 0) {
        const unsigned int* er = (const unsigned int*)(embedB + (size_t)trg[b * 20 + t] * 512);
        ((unsigned int*)(xin + (size_t)b * 1536))[tid] = er[tid];
    }

    __shared__ float part[256];
    __shared__ float ak[100];
    __shared__ float ew[128];
    __shared__ float mxs, inv_s;

    // a_key: 2 threads per output (K halves of 512), bf16 inputs.
    float s = 0.f;
    if (tid < 200) {
        int n = tid >> 1, hh = tid & 1;
        const bf16* wr = akWB + (size_t)n * 1024 + hh * 512;
        const bf16* hr = hb + (size_t)b * 1024 + hh * 512;
#pragma unroll 8
        for (int k = 0; k < 512; ++k) s += b2f(hr[k]) * b2f(wr[k]);
    }
    part[tid] = s;
    __syncthreads();
    if (tid < 100) ak[tid] = tanhf(part[2 * tid] + part[2 * tid + 1] + akb[tid]);
    __syncthreads();

    if (tid < 128) {
        const float* qr = qkB + ((size_t)b * 128 + tid) * 100;
        float e = 0.f;
#pragma unroll 4
        for (int k = 0; k < 100; ++k) e += qr[k] * ak[k];
        ew[tid] = (tid < lens[b]) ? e : -INFINITY;
    }
    __syncthreads();
    if (tid < 64) {
        float m = fmaxf(ew[tid], ew[tid + 64]);
#pragma unroll
        for (int off = 32; off; off >>= 1) m = fmaxf(m, __shfl_down(m, off));
        if (tid == 0) mxs = m;
    }
    __syncthreads();
    if (tid < 128) ew[tid] = expf(ew[tid] - mxs);  // masked -> 0
    __syncthreads();
    if (tid < 64) {
        float s2 = ew[tid] + ew[tid + 64];
#pragma unroll
        for (int off = 32; off; off >>= 1) s2 += __shfl_down(s2, off);
        if (tid == 0) inv_s = 1.0f / s2;
    }
    __syncthreads();

    {
        int jj = (chunk << 8) + tid;
        const bf16* qvb = qvBb + ((size_t)b * 128) * 1024 + jj;
        float a0 = 0.f;
#pragma unroll 4
        for (int s3 = 0; s3 < 128; ++s3) a0 += ew[s3] * b2f(qvb[(size_t)s3 * 1024]);
        a0 *= inv_s;
        bf16 cb = f2b(a0);
        xin[(size_t)b * 1536 + 512 + jj] = cb;
        featT[(size_t)b * 2048 + 1024 + jj] = cb;
    }
}

// ---------------------------------------------------------------------------
// Decoder LSTM step. Grid 256 blocks x 64 thr; gates x 4 j packed in N-tile.
__global__ __launch_bounds__(64) void k_dec_z(const bf16* __restrict__ xin,
                                              const bf16* __restrict__ Wih,
                                              const bf16* __restrict__ hb_in,
                                              const bf16* __restrict__ Whh,
                                              const float* __restrict__ bih,
                                              const float* __restrict__ bhh,
                                              float* __restrict__ cd,
                                              bf16* __restrict__ hb_out,
                                              bf16* __restrict__ featT) {
    __shared__ float zl[32][16];
    int j0 = blockIdx.x * 4;
    int l = threadIdx.x;
    int r = l & 15, ko = (l >> 4) * 8;
    int wrow = (r >> 2) * 1024 + j0 + (r & 3);

    f32x4 acc0 = {0.f, 0.f, 0.f, 0.f}, acc1 = {0.f, 0.f, 0.f, 0.f};
    {
        const bf16* a0 = xin + (size_t)r * 1536 + ko;
        const bf16* a1 = xin + (size_t)(16 + r) * 1536 + ko;
        const bf16* bp = Wih + (size_t)wrow * 1536 + ko;
#pragma unroll 4
        for (int kk = 0; kk < 48; ++kk) {
            bf16x8 bv = ld8(bp + kk * 32);
            acc0 = MFMA(ld8(a0 + kk * 32), bv, acc0);
            acc1 = MFMA(ld8(a1 + kk * 32), bv, acc1);
        }
    }
    {
        const bf16* a0 = hb_in + (size_t)r * 1024 + ko;
        const bf16* a1 = hb_in + (size_t)(16 + r) * 1024 + ko;
        const bf16* bp = Whh + (size_t)wrow * 1024 + ko;
#pragma unroll 4
        for (int kk = 0; kk < 32; ++kk) {
            bf16x8 bv = ld8(bp + kk * 32);
            acc0 = MFMA(ld8(a0 + kk * 32), bv, acc0);
            acc1 = MFMA(ld8(a1 + kk * 32), bv, acc1);
        }
    }
    int ccol = l & 15, cr = (l >> 4) * 4;
#pragma unroll
    for (int q = 0; q < 4; ++q) {
        zl[cr + q][ccol] = acc0[q];
        zl[16 + cr + q][ccol] = acc1[q];
    }
    __syncthreads();

#pragma unroll
    for (int e = l; e < 128; e += 64) {
        int b = e >> 2, jj = e & 3;
        int j = j0 + jj;
        float zi = zl[b][jj]      + bih[j]        + bhh[j];
        float zf = zl[b][4 + jj]  + bih[1024 + j] + bhh[1024 + j];
        float zg = zl[b][8 + jj]  + bih[2048 + j] + bhh[2048 + j];
        float zo = zl[b][12 + jj] + bih[3072 + j] + bhh[3072 + j];
        int hi = b * 1024 + j;
        float co = cd[hi];
        float cn = sigf(zf) * co + sigf(zi) * tanhf(zg);
        float hn = sigf(zo) * tanhf(cn);
        cd[hi] = cn;
        bf16 hnb = f2b(hn);
        hb_out[hi] = hnb;
        featT[(size_t)b * 2048 + j] = hnb;
    }
}

// ---------------------------------------------------------------------------
extern "C" void kernel_launch(void* const* d_in, const int* in_sizes, int n_in,
                              void* d_out, int out_size, void* d_ws, size_t ws_size,
                              hipStream_t stream) {
    const float* embed   = (const float*)d_in[0];
    const float* enc_Wih = (const float*)d_in[1];
    const float* enc_Whh = (const float*)d_in[2];
    const float* enc_bih = (const float*)d_in[3];
    const float* enc_bhh = (const float*)d_in[4];
    const float* dec_Wih = (const float*)d_in[5];
    const float* dec_Whh = (const float*)d_in[6];
    const float* dec_bih = (const float*)d_in[7];
    const float* dec_bhh = (const float*)d_in[8];
    const float* qk_W    = (const float*)d_in[9];
    const float* qk_b    = (const float*)d_in[10];
    const float* qv_W    = (const float*)d_in[11];
    const float* qv_b    = (const float*)d_in[12];
    const float* ak_W    = (const float*)d_in[13];
    const float* ak_b    = (const float*)d_in[14];
    const float* out_W   = (const float*)d_in[15];
    const float* out_b   = (const float*)d_in[16];
    const float* wd_b    = (const float*)d_in[17];
    const float* hfc1_W  = (const float*)d_in[18];
    const float* hfc1_b  = (const float*)d_in[19];
    const float* hfc2_W  = (const float*)d_in[20];
    const float* hfc2_b  = (const float*)d_in[21];
    const float* cfc1_W  = (const float*)d_in[22];
    const float* cfc1_b  = (const float*)d_in[23];
    const float* cfc2_W  = (const float*)d_in[24];
    const float* cfc2_b  = (const float*)d_in[25];
    const int* src  = (const int*)d_in[26];
    const int* lens = (const int*)d_in[27];
    const int* trg  = (const int*)d_in[28];

    char* cur = (char*)d_ws;
    auto alloc = [&](size_t bytes) -> char* {
        char* p = cur;
        cur += (bytes + 255) & ~(size_t)255;
        return p;
    };
    bf16* embedB  = (bf16*)alloc((size_t)16384000 * 2);
    bf16* encWihB = (bf16*)alloc((size_t)2097152 * 2);
    bf16* encWhhB = (bf16*)alloc((size_t)4194304 * 2);
    bf16* decWihB = (bf16*)alloc((size_t)6291456 * 2);
    bf16* decWhhB = (bf16*)alloc((size_t)4194304 * 2);
    bf16* qkWB    = (bf16*)alloc((size_t)102400 * 2);
    bf16* qvWB    = (bf16*)alloc((size_t)1048576 * 2);
    bf16* outWB   = (bf16*)alloc((size_t)1048576 * 2);
    bf16* hfc1B   = (bf16*)alloc((size_t)2097152 * 2);
    bf16* hfc2B   = (bf16*)alloc((size_t)2097152 * 2);
    bf16* cfc1B   = (bf16*)alloc((size_t)2097152 * 2);
    bf16* cfc2B   = (bf16*)alloc((size_t)2097152 * 2);
    bf16* akWB    = (bf16*)alloc((size_t)102400 * 2);
    bf16*  Xsrc  = (bf16*)alloc((size_t)4096 * 512 * 2);
    bf16*  Zx    = (bf16*)alloc((size_t)4096 * 4096 * 2);
    bf16*  SH    = (bf16*)alloc((size_t)4096 * 1024 * 2);
    float* qkB   = (float*)alloc((size_t)4096 * 100 * 4);
    bf16*  qvBb  = (bf16*)alloc((size_t)4096 * 1024 * 2);   // q_value in bf16
    bf16*  hbA   = (bf16*)alloc(32 * 1024 * 2);
    bf16*  hbB   = (bf16*)alloc(32 * 1024 * 2);
    bf16*  cbT   = (bf16*)alloc(32 * 1024 * 2);
    bf16*  t1    = (bf16*)alloc(32 * 2048 * 2);
    float* cd    = (float*)alloc(32 * 1024 * 4);
    bf16*  hdA   = (bf16*)alloc(32 * 1024 * 2);
    bf16*  hdB   = (bf16*)alloc(32 * 1024 * 2);
    bf16*  xin   = (bf16*)alloc(32 * 1536 * 2);
    bf16*  featAll = (bf16*)alloc((size_t)608 * 2048 * 2);  // [t*32+b][h | ctx]
    bf16*  feats = (bf16*)alloc((size_t)608 * 512 * 2);
    int*   flags = (int*)alloc((size_t)128 * 256 * 4);
    if ((size_t)(cur - (char*)d_ws) > ws_size) return;  // workspace too small

    hipMemsetAsync(hbA, 0, 32 * 1024 * 2, stream);
    hipMemsetAsync(flags, 0, (size_t)128 * 256 * 4, stream);

    ConvTable tab;
    tab.d[0]  = {embed,   embedB,  16384000};
    tab.d[1]  = {enc_Wih, encWihB, 2097152};
    tab.d[2]  = {enc_Whh, encWhhB, 4194304};
    tab.d[3]  = {dec_Wih, decWihB, 6291456};
    tab.d[4]  = {dec_Whh, decWhhB, 4194304};
    tab.d[5]  = {qk_W,    qkWB,    102400};
    tab.d[6]  = {qv_W,    qvWB,    1048576};
    tab.d[7]  = {out_W,   outWB,   1048576};
    tab.d[8]  = {hfc1_W,  hfc1B,   2097152};
    tab.d[9]  = {hfc2_W,  hfc2B,   2097152};
    tab.d[10] = {cfc1_W,  cfc1B,   2097152};
    tab.d[11] = {cfc2_W,  cfc2B,   2097152};
    tab.d[12] = {ak_W,    akWB,    102400};
    k_conv<<<dim3(1024, 13), 256, 0, stream>>>(tab);

    k_gather<<<4096, 256, 0, stream>>>((const unsigned int*)embedB, src, (unsigned int*)Xsrc);

    // Zx = Xsrc @ enc_Wih^T  (M=4096, N=4096, K=512), bf16 out
    k_gemm_bt<<<32 * 32, 256, 0, stream>>>(Xsrc, encWihB, nullptr, nullptr, Zx,
                                           4096, 4096, 512, 4096, 32, 3, 0);

    // Persistent encoder (cooperative launch for co-residency only).
    {
        const bf16* ZxA = Zx;  const bf16* WhhA = encWhhB;
        const float* bihA = enc_bih; const float* bhhA = enc_bhh;
        const int* lensA = lens;
        unsigned int* hb0A = (unsigned int*)hbA;
        unsigned int* hb1A = (unsigned int*)hbB;
        bf16* cbTA = cbT; bf16* SHA = SH; int* flagsA = flags;
        void* args[] = {(void*)&ZxA, (void*)&WhhA, (void*)&bihA, (void*)&bhhA,
                        (void*)&lensA, (void*)&hb0A, (void*)&hb1A, (void*)&cbTA,
                        (void*)&SHA, (void*)&flagsA};
        hipLaunchCooperativeKernel((void*)k_enc_all, dim3(256), dim3(256), args, 0, stream);
    }
    bf16* hbT = hbA;  // publish target at t=127 (odd) is hbw0 == hbA

    k_gemm_sm<<<256, 64, 0, stream>>>(hbT, hfc1B, hfc1_b, nullptr, 0, t1, 2048, 1024, 128, 1);
    k_gemm_sm<<<128, 64, 0, stream>>>(t1, hfc2B, hfc2_b, nullptr, 0, hdA, 1024, 2048, 64, 0);
    k_gemm_sm<<<256, 64, 0, stream>>>(cbT, cfc1B, cfc1_b, nullptr, 0, t1, 2048, 1024, 128, 1);
    k_gemm_sm<<<128, 64, 0, stream>>>(t1, cfc2B, cfc2_b, cd, 1024, nullptr, 0, 2048, 64, 0);

    k_gemm_bt<<<32, 256, 0, stream>>>(SH, qkWB, qk_b, qkB, nullptr,
                                      4096, 100, 1024, 100, 1, 1, 0);
    k_gemm_bt<<<256, 256, 0, stream>>>(SH, qvWB, qv_b, nullptr, qvBb,
                                       4096, 1024, 1024, 1024, 8, 3, 0);

    // Decoder: 2 kernels per step (a_key fused into attn; out-GEMM deferred).
    for (int t = 0; t < 19; ++t) {
        const bf16* hin = (t & 1) ? hdB : hdA;
        bf16* hout = (t & 1) ? hdA : hdB;
        bf16* featT = featAll + (size_t)t * 32 * 2048;
        k_attn<<<128, 256, 0, stream>>>(embedB, trg, akWB, ak_b, qkB, qvBb, lens,
                                        hin, xin, featT, t);
        k_dec_z<<<256, 64, 0, stream>>>(xin, decWihB, hin, decWhhB, dec_bih, dec_bhh,
                                        cd, hout, featT);
    }

    // Batched out-projection: feats(608x512) = featAll(608x2048) @ out_W^T.
    k_gemm_bt<<<20, 256, 0, stream>>>(featAll, outWB, out_b, nullptr, feats,
                                      608, 512, 2048, 512, 4, 3, 0);

    // Logits: feats(608x512) @ embed^T(32000x512) + wd_b, XCD-grouped mapping.
    k_gemm_bt<<<1280, 256, 0, stream>>>(feats, embedB, wd_b, (float*)d_out, nullptr,
                                        608, 32000, 512, 0, 250, 2, 1);
}

// Round 17
// 1826.433 us; speedup vs baseline: 2.3789x; 1.1232x over previous
//
#include <hip/hip_runtime.h>
#include <hip/hip_bf16.h>

// Problem constants: B=32, S=128, T=20 (19 dec steps), H=1024, D=512, K_attn=100, V=32000
// Inputs float32; output d_out float32 (B,19,V).
// Encoder: round-13/15 kernel VERBATIM (passing, 713us). Exchange FROZEN
// (5 failed variants: rounds 5/6/7/12/14).
// k_gemm_bt: round-16 LDS-staged version (passing).
// Round 17 (decoder internals, pure-function):
//  - k_attn: a_key dot vectorized (ushort8 16B loads), ctx s-dim split 2-way
//    with LDS reduce, 8 col-chunks (grid 256 = full CU coverage).
//  - k_dec_z: 256 thr / 4 waves, each wave owns a virtual-K quarter
//    (xin 48 + h 32 = 80 K-chunks), LDS partial reduce, fused pointwise.

using bf16 = __hip_bfloat16;
typedef __attribute__((ext_vector_type(8))) __bf16 bf16x8;
typedef __attribute__((ext_vector_type(4))) float f32x4;
typedef __attribute__((ext_vector_type(8))) unsigned short u16x8;

__device__ __forceinline__ bf16x8 ld8(const bf16* p) {
    return *reinterpret_cast<const bf16x8*>(p);
}
__device__ __forceinline__ float b2f(bf16 v) { return __bfloat162float(v); }
__device__ __forceinline__ bf16 f2b(float v) { return __float2bfloat16(v); }
__device__ __forceinline__ unsigned short b2u(bf16 v) {
    unsigned short u; __builtin_memcpy(&u, &v, 2); return u;
}
__device__ __forceinline__ float u2f(unsigned short u) {
    unsigned int x = (unsigned int)u << 16;
    float f; __builtin_memcpy(&f, &x, 4); return f;
}
__device__ __forceinline__ float sigf(float x) { return 1.0f / (1.0f + expf(-x)); }

#define MFMA(a, b, c) __builtin_amdgcn_mfma_f32_16x16x32_bf16((a), (b), (c), 0, 0, 0)

__device__ __forceinline__ void gload_lds16(const bf16* g, bf16* l) {
    __builtin_amdgcn_global_load_lds(
        (const __attribute__((address_space(1))) void*)g,
        (__attribute__((address_space(3))) void*)l, 16, 0, 0);
}

// ---------------------------------------------------------------------------
// f32 -> bf16 conversion for weight tensors. blockIdx.y selects tensor.
struct ConvDesc { const float* src; bf16* dst; int n; };
struct ConvTable { ConvDesc d[13]; };

__global__ __launch_bounds__(256) void k_conv(ConvTable tab) {
    ConvDesc cd = tab.d[blockIdx.y];
    int stride = gridDim.x * blockDim.x * 4;
    for (int i = (blockIdx.x * blockDim.x + threadIdx.x) * 4; i < cd.n; i += stride) {
        float4 v = *reinterpret_cast<const float4*>(cd.src + i);
        bf16 tmp[4] = {f2b(v.x), f2b(v.y), f2b(v.z), f2b(v.w)};
        *reinterpret_cast<ushort4*>(cd.dst + i) = *reinterpret_cast<const ushort4*>(tmp);
    }
}

// ---------------------------------------------------------------------------
// Gather bf16 embedding rows (512 bf16 = 256 u32 per row), one block per row.
__global__ __launch_bounds__(256) void k_gather(const unsigned int* __restrict__ table,
                                                const int* __restrict__ idx,
                                                unsigned int* __restrict__ out) {
    int r = blockIdx.x;
    out[(size_t)r * 256 + threadIdx.x] = table[(size_t)idx[r] * 256 + threadIdx.x];
}

// ---------------------------------------------------------------------------
// LDS-staged tiled GEMM (round-16 version, passing): C = A(MxK) @ Bw(NxK)^T.
__global__ __launch_bounds__(256) void k_gemm_bt(const bf16* __restrict__ A,
                                                 const bf16* __restrict__ Bw,
                                                 const float* __restrict__ bias,
                                                 float* __restrict__ outF,
                                                 bf16* __restrict__ outB,
                                                 int M, int N, int K, int ldo,
                                                 int ntN, int mode, int xcdmap) {
    __shared__ __attribute__((aligned(16))) bf16 ldsA[128 * 32];
    __shared__ __attribute__((aligned(16))) bf16 ldsB[128 * 32];

    int bx = blockIdx.x;
    int mt, nt;
    if (xcdmap) {
        int ntM = (M + 127) >> 7;
        int x = bx & 7, w = bx >> 3;
        mt = w % ntM;
        nt = (w / ntM) * 8 + x;
        if (nt >= ntN) return;
    } else {
        mt = bx / ntN;
        nt = bx % ntN;
    }
    int tid = threadIdx.x, wv = tid >> 6, l = tid & 63;
    int m0 = mt * 128, n0 = nt * 128;
    int m0w = (wv >> 1) * 64;
    int n0w = (wv & 1) * 64;
    int r = l & 15, ko = l >> 4;

    int srow0 = (l >> 2), suc = l & 3;

    f32x4 zv = {0.f, 0.f, 0.f, 0.f};
    f32x4 acc[4][4];
#pragma unroll
    for (int i = 0; i < 4; ++i)
#pragma unroll
        for (int j = 0; j < 4; ++j) acc[i][j] = zv;

    const bf16x8* LA = (const bf16x8*)ldsA;
    const bf16x8* LB = (const bf16x8*)ldsB;

    for (int kk = 0; kk < K; kk += 32) {
        __syncthreads();
#pragma unroll
        for (int c = 0; c < 2; ++c) {
            int rbase = c * 64 + wv * 16;
            int row = rbase + srow0;
            int gcu = (suc ^ (row & 3)) << 3;
            int arow = m0 + row; if (arow > M - 1) arow = M - 1;
            int brow = n0 + row; if (brow > N - 1) brow = N - 1;
            gload_lds16(A + (size_t)arow * K + kk + gcu, ldsA + rbase * 32);
            gload_lds16(Bw + (size_t)brow * K + kk + gcu, ldsB + rbase * 32);
        }
        __syncthreads();

        bf16x8 af[4], bfv[4];
#pragma unroll
        for (int i = 0; i < 4; ++i) {
            int row = m0w + i * 16 + r;
            af[i] = LA[row * 4 + (ko ^ (row & 3))];
        }
#pragma unroll
        for (int j = 0; j < 4; ++j) {
            int row = n0w + j * 16 + r;
            bfv[j] = LB[row * 4 + (ko ^ (row & 3))];
        }
#pragma unroll
        for (int i = 0; i < 4; ++i)
#pragma unroll
            for (int j = 0; j < 4; ++j) acc[i][j] = MFMA(af[i], bfv[j], acc[i][j]);
    }

    int ccol = l & 15, cr = (l >> 4) * 4;
#pragma unroll
    for (int i = 0; i < 4; ++i) {
#pragma unroll
        for (int j = 0; j < 4; ++j) {
            int n = n0 + n0w + j * 16 + ccol;
            if (n >= N) continue;
            float bv = bias ? bias[n] : 0.f;
#pragma unroll
            for (int q = 0; q < 4; ++q) {
                int row = m0 + m0w + i * 16 + cr + q;
                if (row >= M) continue;
                float v = acc[i][j][q] + bv;
                if (mode == 1) v = tanhf(v);
                if (mode == 2) {
                    outF[((size_t)(row & 31) * 19 + (size_t)(row >> 5)) * 32000 + n] = v;
                } else if (mode == 3) {
                    outB[(size_t)row * ldo + n] = f2b(v);
                } else {
                    outF[(size_t)row * ldo + n] = v;
                }
            }
        }
    }
}

// ---------------------------------------------------------------------------
// Small-M GEMM: one 16x16 tile per block (64 threads = 1 wave).
__global__ __launch_bounds__(64) void k_gemm_sm(const bf16* __restrict__ A,
                                                const bf16* __restrict__ W,
                                                const float* __restrict__ bias,
                                                float* __restrict__ outF, int ldof,
                                                bf16* __restrict__ outB, int ldob,
                                                int K, int ntN, int act) {
    int bx = blockIdx.x;
    int mt = bx / ntN, nt = bx % ntN;
    int l = threadIdx.x;
    int r = l & 15, ko = (l >> 4) * 8;
    const bf16* ap = A + (size_t)(mt * 16 + r) * K + ko;
    const bf16* bp = W + (size_t)(nt * 16 + r) * K + ko;
    f32x4 acc = {0.f, 0.f, 0.f, 0.f};
    int nk = K >> 5;
#pragma unroll 4
    for (int kk = 0; kk < nk; ++kk) acc = MFMA(ld8(ap + kk * 32), ld8(bp + kk * 32), acc);
    int n = nt * 16 + (l & 15);
    int cr = (l >> 4) * 4;
    float bv = bias ? bias[n] : 0.f;
#pragma unroll
    for (int q = 0; q < 4; ++q) {
        int row = mt * 16 + cr + q;
        float v = acc[q] + bv;
        if (act == 1) v = fmaxf(v, 0.f);
        if (act == 2) v = tanhf(v);
        if (outF) outF[(size_t)row * ldof + n] = v;
        if (outB) outB[(size_t)row * ldob + n] = f2b(v);
    }
}

// ---------------------------------------------------------------------------
// Persistent encoder, 128 LSTM steps. ROUND-13 VERSION VERBATIM (passing).
// Grid 256 = 4 batch-groups x 64 j-blocks. DO NOT MODIFY THE EXCHANGE.
__global__ __launch_bounds__(256, 1) void k_enc_all(const bf16* __restrict__ Zx,
                                                    const bf16* __restrict__ Whh,
                                                    const float* __restrict__ bih,
                                                    const float* __restrict__ bhh,
                                                    const int* __restrict__ lens,
                                                    unsigned int* __restrict__ hbw0,
                                                    unsigned int* __restrict__ hbw1,
                                                    bf16* __restrict__ cbT,
                                                    bf16* __restrict__ SH,
                                                    int* __restrict__ flags) {
    __shared__ bf16 hlds[8][1024];           // 16KB staged group h, swizzled 16B units
    __shared__ float zl[4][8][16];           // 2KB gate outputs
    __shared__ unsigned short hpub[8][16];   // publish staging
    unsigned int* hldsw = (unsigned int*)hlds;
    const bf16x8* hldsv = (const bf16x8*)hlds;

    int bid = blockIdx.x;
    int grp = bid >> 6, jblk = bid & 63;
    int j0 = jblk * 16;
    int tid = threadIdx.x;
    int g = tid >> 6, l = tid & 63;
    int r = l & 15, ko = (l >> 4) * 8;

    // Whh slice -> registers (16 rows x 1024 K per wave), loaded once.
    bf16x8 wreg[32];
    {
        const bf16* wp = Whh + (size_t)(g * 1024 + j0 + r) * 1024 + ko;
#pragma unroll
        for (int kk = 0; kk < 32; ++kk) wreg[kk] = ld8(wp + kk * 32);
    }

    // Pointwise ownership (tid < 128): one (batch, j) element.
    int bl = tid >> 4, ji = tid & 15;   // bl in [0,8) for tid<128
    int b = grp * 8 + bl;
    int j = j0 + ji;
    bool pw = tid < 128;
    float bs[4] = {0.f, 0.f, 0.f, 0.f};
    int lenv = 0;
    float hs = 0.f, cs = 0.f;
    const bf16* zxp = Zx;
    if (pw) {
#pragma unroll
        for (int gg = 0; gg < 4; ++gg) bs[gg] = bih[gg * 1024 + j] + bhh[gg * 1024 + j];
        lenv = lens[b];
        zxp = Zx + (size_t)(b * 128) * 4096 + j;
    }
    int ccol = l & 15, cr = (l >> 4) * 4;
    int rk = r & 7;                       // XOR swizzle key (row & 7)
    unsigned int gbase = grp * 4096;      // group's u32 offset into h buffers

    for (int t = 0; t < 128; ++t) {
        // Prefetch Zx[t] (independent of barrier) — hides latency under spin.
        float za[4] = {0.f, 0.f, 0.f, 0.f};
        if (pw) {
#pragma unroll
            for (int gg = 0; gg < 4; ++gg)
                za[gg] = b2f(zxp[(size_t)t * 4096 + gg * 1024]);
        }

        // Wait for this group's 64 producers of h_t (t=0: initial zeros).
        if (t > 0) {
            if (tid < 64) {
                const int* fp = flags + (t - 1) * 256 + grp * 64;
                while (true) {
                    int v = __hip_atomic_load(fp + l, __ATOMIC_RELAXED,
                                              __HIP_MEMORY_SCOPE_AGENT);
                    if (__all(v != 0)) break;
                    __builtin_amdgcn_s_sleep(1);
                }
                __builtin_amdgcn_sched_barrier(0);  // pin compile-time order
            }
            __syncthreads();
        }

        // Stage group h_t (4096 u32) LLC -> LDS, swizzled: unit u -> u^(row&7).
        // PROVEN interleaved form (unroll 4, one load one write) — DO NOT
        // reschedule (rounds 5/6/7/12/14 all corrupted deterministically).
        const unsigned int* hw = ((t & 1) ? hbw1 : hbw0) + gbase;
#pragma unroll 4
        for (int i = 0; i < 16; ++i) {
            int d = i * 256 + tid;
            int bb = d >> 9, w = d & 511;
            unsigned int v = __hip_atomic_load(hw + d, __ATOMIC_RELAXED,
                                               __HIP_MEMORY_SCOPE_AGENT);
            hldsw[bb * 512 + ((((w >> 2) ^ (bb & 7)) << 2) | (w & 3))] = v;
        }
        __syncthreads();

        // z[g] slice = h @ Whh[g-slice]^T from LDS. Only 8 valid M rows;
        // lanes with (l&15)>=8 read aliased rows (results discarded).
        f32x4 acc0 = {0.f, 0.f, 0.f, 0.f};
#pragma unroll
        for (int kk = 0; kk < 32; ++kk) {
            int u = kk * 4 + (l >> 4);
            acc0 = MFMA(hldsv[(r & 7) * 128 + (u ^ rk)], wreg[kk], acc0);
        }
        if (l < 32) {
#pragma unroll
            for (int q = 0; q < 4; ++q) zl[g][cr + q][ccol] = acc0[q];
        }
        __syncthreads();

        // Fused pointwise: one (b, j) element per thread (tid < 128).
        if (pw) {
            float zi = zl[0][bl][ji] + za[0] + bs[0];
            float zf = zl[1][bl][ji] + za[1] + bs[1];
            float zg = zl[2][bl][ji] + za[2] + bs[2];
            float zo = zl[3][bl][ji] + za[3] + bs[3];
            float cn = sigf(zf) * cs + sigf(zi) * tanhf(zg);
            float hn = sigf(zo) * tanhf(cn);
            bool msk = t < lenv;
            if (msk) { hs = hn; cs = cn; }
            hpub[bl][ji] = b2u(f2b(hs));
            SH[((size_t)b * 128 + t) * 1024 + j] = msk ? f2b(hn) : f2b(0.f);
            if (t == 127) cbT[b * 1024 + j] = f2b(cs);
        }
        __syncthreads();

        // Publish this block's h_{t+1} slice (8 b x 16 j = 64 u32) to LLC.
        unsigned int* hwn = ((t & 1) ? hbw0 : hbw1) + gbase;
        if (tid < 64) {
            int pb = tid >> 3, pq = tid & 7;
            unsigned int val = (unsigned int)hpub[pb][2 * pq] |
                               ((unsigned int)hpub[pb][2 * pq + 1] << 16);
            __hip_atomic_store(hwn + (size_t)pb * 512 + (j0 >> 1) + pq, val,
                               __ATOMIC_RELAXED, __HIP_MEMORY_SCOPE_AGENT);
        }
        __syncthreads();  // vmcnt(0) drain: publish stores acked at LLC
        if (tid == 0)
            __hip_atomic_fetch_add(flags + t * 256 + grp * 64 + jblk, 1,
                                   __ATOMIC_RELAXED, __HIP_MEMORY_SCOPE_AGENT);
    }
}

// ---------------------------------------------------------------------------
// Decoder attention step. Grid 256 = 32 b x 8 col-chunks (128 cols each).
// a_key vectorized (ushort8 16B loads); ctx s-dim split 2-way + LDS reduce.
__global__ __launch_bounds__(256) void k_attn(const bf16* __restrict__ embedB,
                                              const int* __restrict__ trg,
                                              const bf16* __restrict__ akWB,
                                              const float* __restrict__ akb,
                                              const float* __restrict__ qkB,
                                              const bf16* __restrict__ qvBb,
                                              const int* __restrict__ lens,
                                              const bf16* __restrict__ hb,
                                              bf16* __restrict__ xin,
                                              bf16* __restrict__ featT, int t) {
    int b = blockIdx.x >> 3, chunk = blockIdx.x & 7;
    int tid = threadIdx.x;
    if (chunk == 0) {
        const unsigned int* er = (const unsigned int*)(embedB + (size_t)trg[b * 20 + t] * 512);
        ((unsigned int*)(xin + (size_t)b * 1536))[tid] = er[tid];
    }

    __shared__ float part[256];
    __shared__ float ak[100];
    __shared__ float ew[128];
    __shared__ float mxs, inv_s;

    // a_key: 2 threads per output (K halves of 512), vectorized 16B loads.
    float s = 0.f;
    if (tid < 200) {
        int n = tid >> 1, hh = tid & 1;
        const u16x8* wr = (const u16x8*)(akWB + (size_t)n * 1024 + hh * 512);
        const u16x8* hr = (const u16x8*)(hb + (size_t)b * 1024 + hh * 512);
#pragma unroll 8
        for (int k = 0; k < 64; ++k) {
            u16x8 wv8 = wr[k], hv8 = hr[k];
#pragma unroll
            for (int e = 0; e < 8; ++e) s += u2f(hv8[e]) * u2f(wv8[e]);
        }
    }
    part[tid] = s;
    __syncthreads();
    if (tid < 100) ak[tid] = tanhf(part[2 * tid] + part[2 * tid + 1] + akb[tid]);
    __syncthreads();

    if (tid < 128) {
        const float* qr = qkB + ((size_t)b * 128 + tid) * 100;
        float e = 0.f;
#pragma unroll 4
        for (int k = 0; k < 100; ++k) e += qr[k] * ak[k];
        ew[tid] = (tid < lens[b]) ? e : -INFINITY;
    }
    __syncthreads();
    if (tid < 64) {
        float m = fmaxf(ew[tid], ew[tid + 64]);
#pragma unroll
        for (int off = 32; off; off >>= 1) m = fmaxf(m, __shfl_down(m, off));
        if (tid == 0) mxs = m;
    }
    __syncthreads();
    if (tid < 128) ew[tid] = expf(ew[tid] - mxs);  // masked -> 0
    __syncthreads();
    if (tid < 64) {
        float s2 = ew[tid] + ew[tid + 64];
#pragma unroll
        for (int off = 32; off; off >>= 1) s2 += __shfl_down(s2, off);
        if (tid == 0) inv_s = 1.0f / s2;
    }
    __syncthreads();

    // ctx: 128 cols per chunk, thread = (col, s-half); each sums 64 s-values.
    {
        int col = tid & 127, sh2 = tid >> 7;
        int jj = (chunk << 7) + col;
        const bf16* qvb = qvBb + ((size_t)b * 128 + sh2 * 64) * 1024 + jj;
        float a0 = 0.f;
#pragma unroll 8
        for (int s3 = 0; s3 < 64; ++s3)
            a0 += ew[sh2 * 64 + s3] * b2f(qvb[(size_t)s3 * 1024]);
        part[tid] = a0;
    }
    __syncthreads();
    if (tid < 128) {
        int jj = (chunk << 7) + tid;
        float v = (part[tid] + part[tid + 128]) * inv_s;
        bf16 cb = f2b(v);
        xin[(size_t)b * 1536 + 512 + jj] = cb;
        featT[(size_t)b * 2048 + 1024 + jj] = cb;
    }
}

// ---------------------------------------------------------------------------
// Decoder LSTM step. Grid 256 blocks x 256 thr (4 waves). Gates x 4 j packed
// in the 16-row N-tile; each wave owns a virtual-K quarter (xin 48 + h 32 =
// 80 chunks of K=32); LDS partial reduce, then fused pointwise.
__global__ __launch_bounds__(256) void k_dec_z(const bf16* __restrict__ xin,
                                               const bf16* __restrict__ Wih,
                                               const bf16* __restrict__ hb_in,
                                               const bf16* __restrict__ Whh,
                                               const float* __restrict__ bih,
                                               const float* __restrict__ bhh,
                                               float* __restrict__ cd,
                                               bf16* __restrict__ hb_out,
                                               bf16* __restrict__ featT) {
    __shared__ float zp[4][32][16];   // per-wave partials (8KB)
    int j0 = blockIdx.x * 4;
    int tid = threadIdx.x;
    int wv = tid >> 6, l = tid & 63;
    int r = l & 15, ko = (l >> 4) * 8;
    int wrow = (r >> 2) * 1024 + j0 + (r & 3);

    f32x4 acc0 = {0.f, 0.f, 0.f, 0.f}, acc1 = {0.f, 0.f, 0.f, 0.f};
    int k0 = wv * 20, k1 = k0 + 20;
#pragma unroll 4
    for (int k = k0; k < k1; ++k) {
        const bf16 *a0p, *a1p, *bp;
        if (k < 48) {
            a0p = xin + (size_t)r * 1536 + k * 32 + ko;
            a1p = xin + (size_t)(16 + r) * 1536 + k * 32 + ko;
            bp = Wih + (size_t)wrow * 1536 + k * 32 + ko;
        } else {
            int kh = k - 48;
            a0p = hb_in + (size_t)r * 1024 + kh * 32 + ko;
            a1p = hb_in + (size_t)(16 + r) * 1024 + kh * 32 + ko;
            bp = Whh + (size_t)wrow * 1024 + kh * 32 + ko;
        }
        bf16x8 bv = ld8(bp);
        acc0 = MFMA(ld8(a0p), bv, acc0);
        acc1 = MFMA(ld8(a1p), bv, acc1);
    }
    int ccol = l & 15, cr = (l >> 4) * 4;
#pragma unroll
    for (int q = 0; q < 4; ++q) {
        zp[wv][cr + q][ccol] = acc0[q];
        zp[wv][16 + cr + q][ccol] = acc1[q];
    }
    __syncthreads();

    // Fused pointwise: 128 outputs (32 b x 4 jj), tid < 128.
    if (tid < 128) {
        int b = tid >> 2, jj = tid & 3;
        int j = j0 + jj;
        float zi = zp[0][b][jj] + zp[1][b][jj] + zp[2][b][jj] + zp[3][b][jj]
                   + bih[j] + bhh[j];
        float zf = zp[0][b][4 + jj] + zp[1][b][4 + jj] + zp[2][b][4 + jj] +
                   zp[3][b][4 + jj] + bih[1024 + j] + bhh[1024 + j];
        float zg = zp[0][b][8 + jj] + zp[1][b][8 + jj] + zp[2][b][8 + jj] +
                   zp[3][b][8 + jj] + bih[2048 + j] + bhh[2048 + j];
        float zo = zp[0][b][12 + jj] + zp[1][b][12 + jj] + zp[2][b][12 + jj] +
                   zp[3][b][12 + jj] + bih[3072 + j] + bhh[3072 + j];
        int hi = b * 1024 + j;
        float co = cd[hi];
        float cn = sigf(zf) * co + sigf(zi) * tanhf(zg);
        float hn = sigf(zo) * tanhf(cn);
        cd[hi] = cn;
        bf16 hnb = f2b(hn);
        hb_out[hi] = hnb;
        featT[(size_t)b * 2048 + j] = hnb;
    }
}

// ---------------------------------------------------------------------------
extern "C" void kernel_launch(void* const* d_in, const int* in_sizes, int n_in,
                              void* d_out, int out_size, void* d_ws, size_t ws_size,
                              hipStream_t stream) {
    const float* embed   = (const float*)d_in[0];
    const float* enc_Wih = (const float*)d_in[1];
    const float* enc_Whh = (const float*)d_in[2];
    const float* enc_bih = (const float*)d_in[3];
    const float* enc_bhh = (const float*)d_in[4];
    const float* dec_Wih = (const float*)d_in[5];
    const float* dec_Whh = (const float*)d_in[6];
    const float* dec_bih = (const float*)d_in[7];
    const float* dec_bhh = (const float*)d_in[8];
    const float* qk_W    = (const float*)d_in[9];
    const float* qk_b    = (const float*)d_in[10];
    const float* qv_W    = (const float*)d_in[11];
    const float* qv_b    = (const float*)d_in[12];
    const float* ak_W    = (const float*)d_in[13];
    const float* ak_b    = (const float*)d_in[14];
    const float* out_W   = (const float*)d_in[15];
    const float* out_b   = (const float*)d_in[16];
    const float* wd_b    = (const float*)d_in[17];
    const float* hfc1_W  = (const float*)d_in[18];
    const float* hfc1_b  = (const float*)d_in[19];
    const float* hfc2_W  = (const float*)d_in[20];
    const float* hfc2_b  = (const float*)d_in[21];
    const float* cfc1_W  = (const float*)d_in[22];
    const float* cfc1_b  = (const float*)d_in[23];
    const float* cfc2_W  = (const float*)d_in[24];
    const float* cfc2_b  = (const float*)d_in[25];
    const int* src  = (const int*)d_in[26];
    const int* lens = (const int*)d_in[27];
    const int* trg  = (const int*)d_in[28];

    char* cur = (char*)d_ws;
    auto alloc = [&](size_t bytes) -> char* {
        char* p = cur;
        cur += (bytes + 255) & ~(size_t)255;
        return p;
    };
    bf16* embedB  = (bf16*)alloc((size_t)16384000 * 2);
    bf16* encWihB = (bf16*)alloc((size_t)2097152 * 2);
    bf16* encWhhB = (bf16*)alloc((size_t)4194304 * 2);
    bf16* decWihB = (bf16*)alloc((size_t)6291456 * 2);
    bf16* decWhhB = (bf16*)alloc((size_t)4194304 * 2);
    bf16* qkWB    = (bf16*)alloc((size_t)102400 * 2);
    bf16* qvWB    = (bf16*)alloc((size_t)1048576 * 2);
    bf16* outWB   = (bf16*)alloc((size_t)1048576 * 2);
    bf16* hfc1B   = (bf16*)alloc((size_t)2097152 * 2);
    bf16* hfc2B   = (bf16*)alloc((size_t)2097152 * 2);
    bf16* cfc1B   = (bf16*)alloc((size_t)2097152 * 2);
    bf16* cfc2B   = (bf16*)alloc((size_t)2097152 * 2);
    bf16* akWB    = (bf16*)alloc((size_t)102400 * 2);
    bf16*  Xsrc  = (bf16*)alloc((size_t)4096 * 512 * 2);
    bf16*  Zx    = (bf16*)alloc((size_t)4096 * 4096 * 2);
    bf16*  SH    = (bf16*)alloc((size_t)4096 * 1024 * 2);
    float* qkB   = (float*)alloc((size_t)4096 * 100 * 4);
    bf16*  qvBb  = (bf16*)alloc((size_t)4096 * 1024 * 2);   // q_value in bf16
    bf16*  hbA   = (bf16*)alloc(32 * 1024 * 2);
    bf16*  hbB   = (bf16*)alloc(32 * 1024 * 2);
    bf16*  cbT   = (bf16*)alloc(32 * 1024 * 2);
    bf16*  t1    = (bf16*)alloc(32 * 2048 * 2);
    float* cd    = (float*)alloc(32 * 1024 * 4);
    bf16*  hdA   = (bf16*)alloc(32 * 1024 * 2);
    bf16*  hdB   = (bf16*)alloc(32 * 1024 * 2);
    bf16*  xin   = (bf16*)alloc(32 * 1536 * 2);
    bf16*  featAll = (bf16*)alloc((size_t)608 * 2048 * 2);  // [t*32+b][h | ctx]
    bf16*  feats = (bf16*)alloc((size_t)608 * 512 * 2);
    int*   flags = (int*)alloc((size_t)128 * 256 * 4);
    if ((size_t)(cur - (char*)d_ws) > ws_size) return;  // workspace too small

    hipMemsetAsync(hbA, 0, 32 * 1024 * 2, stream);
    hipMemsetAsync(flags, 0, (size_t)128 * 256 * 4, stream);

    ConvTable tab;
    tab.d[0]  = {embed,   embedB,  16384000};
    tab.d[1]  = {enc_Wih, encWihB, 2097152};
    tab.d[2]  = {enc_Whh, encWhhB, 4194304};
    tab.d[3]  = {dec_Wih, decWihB, 6291456};
    tab.d[4]  = {dec_Whh, decWhhB, 4194304};
    tab.d[5]  = {qk_W,    qkWB,    102400};
    tab.d[6]  = {qv_W,    qvWB,    1048576};
    tab.d[7]  = {out_W,   outWB,   1048576};
    tab.d[8]  = {hfc1_W,  hfc1B,   2097152};
    tab.d[9]  = {hfc2_W,  hfc2B,   2097152};
    tab.d[10] = {cfc1_W,  cfc1B,   2097152};
    tab.d[11] = {cfc2_W,  cfc2B,   2097152};
    tab.d[12] = {ak_W,    akWB,    102400};
    k_conv<<<dim3(1024, 13), 256, 0, stream>>>(tab);

    k_gather<<<4096, 256, 0, stream>>>((const unsigned int*)embedB, src, (unsigned int*)Xsrc);

    // Zx = Xsrc @ enc_Wih^T  (M=4096, N=4096, K=512), bf16 out
    k_gemm_bt<<<32 * 32, 256, 0, stream>>>(Xsrc, encWihB, nullptr, nullptr, Zx,
                                           4096, 4096, 512, 4096, 32, 3, 0);

    // Persistent encoder (cooperative launch for co-residency only).
    {
        const bf16* ZxA = Zx;  const bf16* WhhA = encWhhB;
        const float* bihA = enc_bih; const float* bhhA = enc_bhh;
        const int* lensA = lens;
        unsigned int* hb0A = (unsigned int*)hbA;
        unsigned int* hb1A = (unsigned int*)hbB;
        bf16* cbTA = cbT; bf16* SHA = SH; int* flagsA = flags;
        void* args[] = {(void*)&ZxA, (void*)&WhhA, (void*)&bihA, (void*)&bhhA,
                        (void*)&lensA, (void*)&hb0A, (void*)&hb1A, (void*)&cbTA,
                        (void*)&SHA, (void*)&flagsA};
        hipLaunchCooperativeKernel((void*)k_enc_all, dim3(256), dim3(256), args, 0, stream);
    }
    bf16* hbT = hbA;  // publish target at t=127 (odd) is hbw0 == hbA

    k_gemm_sm<<<256, 64, 0, stream>>>(hbT, hfc1B, hfc1_b, nullptr, 0, t1, 2048, 1024, 128, 1);
    k_gemm_sm<<<128, 64, 0, stream>>>(t1, hfc2B, hfc2_b, nullptr, 0, hdA, 1024, 2048, 64, 0);
    k_gemm_sm<<<256, 64, 0, stream>>>(cbT, cfc1B, cfc1_b, nullptr, 0, t1, 2048, 1024, 128, 1);
    k_gemm_sm<<<128, 64, 0, stream>>>(t1, cfc2B, cfc2_b, cd, 1024, nullptr, 0, 2048, 64, 0);

    k_gemm_bt<<<32, 256, 0, stream>>>(SH, qkWB, qk_b, qkB, nullptr,
                                      4096, 100, 1024, 100, 1, 1, 0);
    k_gemm_bt<<<256, 256, 0, stream>>>(SH, qvWB, qv_b, nullptr, qvBb,
                                       4096, 1024, 1024, 1024, 8, 3, 0);

    // Decoder: 2 kernels per step (a_key fused into attn; out-GEMM deferred).
    for (int t = 0; t < 19; ++t) {
        const bf16* hin = (t & 1) ? hdB : hdA;
        bf16* hout = (t & 1) ? hdA : hdB;
        bf16* featT = featAll + (size_t)t * 32 * 2048;
        k_attn<<<256, 256, 0, stream>>>(embedB, trg, akWB, ak_b, qkB, qvBb, lens,
                                        hin, xin, featT, t);
        k_dec_z<<<256, 256, 0, stream>>>(xin, decWihB, hin, decWhhB, dec_bih, dec_bhh,
                                         cd, hout, featT);
    }

    // Batched out-projection: feats(608x512) = featAll(608x2048) @ out_W^T.
    k_gemm_bt<<<20, 256, 0, stream>>>(featAll, outWB, out_b, nullptr, feats,
                                      608, 512, 2048, 512, 4, 3, 0);

    // Logits: feats(608x512) @ embed^T(32000x512) + wd_b, XCD-grouped mapping.
    k_gemm_bt<<<1280, 256, 0, stream>>>(feats, embedB, wd_b, (float*)d_out, nullptr,
                                        608, 32000, 512, 0, 250, 2, 1);
}